// Round 2
// baseline (1185.900 us; speedup 1.0000x reference)
//
#include <hip/hip_runtime.h>
#include <math.h>

#define NN 128
#define FF 64
#define KK 50
#define EPSV 1e-6f

// ws layout (floats):
// dws: [B*N*N]      off 0         (524288)
// S:   [B*N*N]      off 524288
// P:   [B*N*4*64]   off 1048576   (g, p1, p2, p3 per atom)
// C:   [B*N*3*64]   off 2097152
// Fr:  [B*N*3]      off 2883584

__device__ __forceinline__ float softplusf(float z) {
    // max(z,0) + log1p(exp(-|z|)) -- numerically stable & accurate
    float e = expf(-fabsf(z));
    float l = log1pf(e);
    return (z > 0.f) ? z + l : l;
}

__global__ __launch_bounds__(256) void k_dist(const float* __restrict__ xs, float* __restrict__ dws)
{
    int tid = blockIdx.x * 256 + threadIdx.x;
    int b = tid >> 14;
    int rem = tid & 16383;
    int i = rem >> 7, a = rem & 127;
    const float* xb = xs + b * (NN * 3);
    float dx = xb[i*3+0] - xb[a*3+0];
    float dy = xb[i*3+1] - xb[a*3+1];
    float dz = xb[i*3+2] - xb[a*3+2];
    dws[tid] = sqrtf(dx*dx + dy*dy + dz*dz + EPSV);
}

__global__ __launch_bounds__(256) void k_fwd(
    const float* __restrict__ dws,
    const float* __restrict__ mus, const float* __restrict__ gamma,
    const float* __restrict__ W1a, const float* __restrict__ W1b, const float* __restrict__ W1c,
    const float* __restrict__ b1a, const float* __restrict__ b1b, const float* __restrict__ b1c,
    const float* __restrict__ W2a, const float* __restrict__ W2b, const float* __restrict__ W2c,
    const float* __restrict__ b2a, const float* __restrict__ b2b, const float* __restrict__ b2c,
    const float* __restrict__ Wenc, const float* __restrict__ benc,
    const float* __restrict__ Wt1, const float* __restrict__ bt1, const float* __restrict__ Wt2,
    float* __restrict__ Pout)
{
    __shared__ float w1s[3 * KK * FF];
    __shared__ float mus_s[KK];
    __shared__ float rbf_s[4][4][KK];
    __shared__ float dsh[4][4];
    __shared__ double epid[4][FF];

    int tid = threadIdx.x;
    for (int idx = tid; idx < KK * FF; idx += 256) {
        w1s[idx]             = W1a[idx];
        w1s[KK*FF + idx]     = W1b[idx];
        w1s[2*KK*FF + idx]   = W1c[idx];
    }
    if (tid < KK) mus_s[tid] = mus[tid];
    __syncthreads();

    int wave = tid >> 6, lane = tid & 63, f = lane;
    int atom = blockIdx.x * 4 + wave;
    int i = atom & 127;
    float gam = gamma[0];
    float bb0 = b1a[f], bb1 = b1b[f], bb2 = b1c[f];
    double us0 = 0.0, us1 = 0.0, us2 = 0.0;
    const float* drow = dws + (atom << 7);

    for (int t = 0; t < 32; ++t) {
        if (lane < 4) {
            int aa = (i + 1 + 4*t + lane) & 127;
            dsh[wave][lane] = drow[aa];
        }
        #pragma unroll
        for (int pass = 0; pass < 4; ++pass) {
            int idx = lane + (pass << 6);
            if (idx < 200) {
                int p = idx / 50, k = idx - 50 * p;
                float dd = dsh[wave][p] - mus_s[k];
                rbf_s[wave][p][k] = expf(-gam * dd * dd);
            }
        }
        float z[3][4];
        #pragma unroll
        for (int p = 0; p < 4; ++p) { z[0][p] = bb0; z[1][p] = bb1; z[2][p] = bb2; }
        for (int k = 0; k < KK; ++k) {
            float wv0 = w1s[k*64 + f];
            float wv1 = w1s[KK*FF + k*64 + f];
            float wv2 = w1s[2*KK*FF + k*64 + f];
            #pragma unroll
            for (int p = 0; p < 4; ++p) {
                float rk = rbf_s[wave][p][k];
                z[0][p] = fmaf(rk, wv0, z[0][p]);
                z[1][p] = fmaf(rk, wv1, z[1][p]);
                z[2][p] = fmaf(rk, wv2, z[2][p]);
            }
        }
        int base = 4 * t;
        #pragma unroll
        for (int p = 0; p < 4; ++p) {
            if (base + p < 127) {
                us0 += (double)softplusf(z[0][p]);
                us1 += (double)softplusf(z[1][p]);
                us2 += (double)softplusf(z[2][p]);
            }
        }
    }

    // per-atom epilogue (wave-local, double precision)
    double wf0, wf1, wf2;
    {
        epid[wave][lane] = us0;
        double acc = 0.0;
        for (int m = 0; m < 64; ++m) acc += epid[wave][m] * (double)W2a[m*64 + f];
        wf0 = 1.0 + acc + 127.0 * (double)b2a[f];

        epid[wave][lane] = us1;
        double acc1 = 0.0;
        for (int m = 0; m < 64; ++m) acc1 += epid[wave][m] * (double)W2b[m*64 + f];
        wf1 = 1.0 + acc1 + 127.0 * (double)b2b[f];

        epid[wave][lane] = us2;
        double acc2 = 0.0;
        for (int m = 0; m < 64; ++m) acc2 += epid[wave][m] * (double)W2c[m*64 + f];
        wf2 = 1.0 + acc2 + 127.0 * (double)b2c[f];
    }
    double h0 = (double)Wenc[f] + (double)benc[f];
    double h  = h0 * wf0 * wf1 * wf2;
    epid[wave][lane] = h;
    double pre = (double)bt1[lane];
    for (int m = 0; m < 64; ++m) pre += epid[wave][m] * (double)Wt1[m*64 + lane];
    double tv = tanh(pre);
    double gv = (1.0 - tv * tv) * (double)Wt2[lane];

    float* po = Pout + atom * 256;
    po[lane]       = (float)gv;
    po[64 + lane]  = (float)(h0 * wf1 * wf2);
    po[128 + lane] = (float)(h0 * wf0 * wf2);
    po[192 + lane] = (float)(h0 * wf0 * wf1);
}

// per-atom GEMM-ish: dvdh = g @ Wt1^T ; q_l = dvdh * p_l ; c_l = W2_l @ q_l
__global__ __launch_bounds__(256) void k_atom(
    const float* __restrict__ Wt1,
    const float* __restrict__ W2a, const float* __restrict__ W2b, const float* __restrict__ W2c,
    const float* __restrict__ P, float* __restrict__ C)
{
    __shared__ float L[64 * 65];   // L[o*65+f] = Wt1[f,o]
    __shared__ float W[64 * 65];   // W[f*65+m] = W2l[m,f]
    __shared__ float tmp[4][64];
    int tid = threadIdx.x;
    for (int idx = tid; idx < 4096; idx += 256) {
        int r = idx >> 6, c = idx & 63;
        L[c * 65 + r] = Wt1[idx];   // Wt1[r,c] -> L[c*65+r]
    }
    __syncthreads();
    int wave = tid >> 6, lane = tid & 63;
    float dv[16];
    #pragma unroll
    for (int rep = 0; rep < 16; ++rep) {
        int atom = blockIdx.x * 64 + rep * 4 + wave;
        float gval = P[atom * 256 + lane];
        tmp[wave][lane] = gval;
        float acc = 0.f;
        for (int m = 0; m < 64; ++m) acc = fmaf(tmp[wave][m], L[m * 65 + lane], acc);
        dv[rep] = acc;
    }
    const float* W2p[3] = { W2a, W2b, W2c };
    for (int l = 0; l < 3; ++l) {
        __syncthreads();
        for (int idx = tid; idx < 4096; idx += 256) {
            int r = idx >> 6, c = idx & 63;
            W[c * 65 + r] = W2p[l][idx];   // W2l[r,c] -> W[c*65+r]
        }
        __syncthreads();
        #pragma unroll
        for (int rep = 0; rep < 16; ++rep) {
            int atom = blockIdx.x * 64 + rep * 4 + wave;
            float q = dv[rep] * P[atom * 256 + 64 + l * 64 + lane];
            tmp[wave][lane] = q;
            float acc = 0.f;
            for (int m = 0; m < 64; ++m) acc = fmaf(tmp[wave][m], W[m * 65 + lane], acc);
            C[atom * 192 + l * 64 + lane] = acc;
        }
    }
}

__global__ __launch_bounds__(256) void k_bwd(
    const float* __restrict__ dws,
    const float* __restrict__ mus, const float* __restrict__ gamma,
    const float* __restrict__ W1a, const float* __restrict__ W1b, const float* __restrict__ W1c,
    const float* __restrict__ b1a, const float* __restrict__ b1b, const float* __restrict__ b1c,
    const float* __restrict__ C, float* __restrict__ S)
{
    __shared__ float w1s[3 * KK * FF];
    __shared__ float mus_s[KK];
    __shared__ float rbf_s[4][4][KK];
    __shared__ float rho_s[4][4][KK];
    __shared__ float dsh[4][4];
    int tid = threadIdx.x;
    for (int idx = tid; idx < KK * FF; idx += 256) {
        w1s[idx]           = W1a[idx];
        w1s[KK*FF + idx]   = W1b[idx];
        w1s[2*KK*FF + idx] = W1c[idx];
    }
    if (tid < KK) mus_s[tid] = mus[tid];
    __syncthreads();
    int wave = tid >> 6, lane = tid & 63, f = lane;
    int atom = blockIdx.x * 4 + wave;
    int i = atom & 127;
    float gam = gamma[0];
    float c0 = C[atom*192 + f], c1 = C[atom*192 + 64 + f], c2 = C[atom*192 + 128 + f];
    float bb0 = b1a[f], bb1 = b1b[f], bb2 = b1c[f];
    const float* drow = dws + (atom << 7);
    float* srow = S + (atom << 7);

    for (int t = 0; t < 32; ++t) {
        if (lane < 4) {
            int aa = (i + 1 + 4*t + lane) & 127;
            dsh[wave][lane] = drow[aa];
        }
        #pragma unroll
        for (int pass = 0; pass < 4; ++pass) {
            int idx = lane + (pass << 6);
            if (idx < 200) {
                int p = idx / 50, k = idx - 50 * p;
                float dd = dsh[wave][p] - mus_s[k];
                float e = expf(-gam * dd * dd);
                rbf_s[wave][p][k] = e;
                rho_s[wave][p][k] = -2.f * gam * dd * e;
            }
        }
        float z[3][4], y[3][4];
        #pragma unroll
        for (int p = 0; p < 4; ++p) {
            z[0][p] = bb0; z[1][p] = bb1; z[2][p] = bb2;
            y[0][p] = 0.f; y[1][p] = 0.f; y[2][p] = 0.f;
        }
        for (int k = 0; k < KK; ++k) {
            float wv0 = w1s[k*64 + f];
            float wv1 = w1s[KK*FF + k*64 + f];
            float wv2 = w1s[2*KK*FF + k*64 + f];
            #pragma unroll
            for (int p = 0; p < 4; ++p) {
                float rk = rbf_s[wave][p][k];
                float qk = rho_s[wave][p][k];
                z[0][p] = fmaf(rk, wv0, z[0][p]);
                z[1][p] = fmaf(rk, wv1, z[1][p]);
                z[2][p] = fmaf(rk, wv2, z[2][p]);
                y[0][p] = fmaf(qk, wv0, y[0][p]);
                y[1][p] = fmaf(qk, wv1, y[1][p]);
                y[2][p] = fmaf(qk, wv2, y[2][p]);
            }
        }
        float part[4];
        #pragma unroll
        for (int p = 0; p < 4; ++p) {
            float s0 = 1.f / (1.f + expf(-z[0][p]));
            float s1 = 1.f / (1.f + expf(-z[1][p]));
            float s2 = 1.f / (1.f + expf(-z[2][p]));
            part[p] = c0 * s0 * y[0][p] + c1 * s1 * y[1][p] + c2 * s2 * y[2][p];
        }
        #pragma unroll
        for (int p = 0; p < 4; ++p) {
            #pragma unroll
            for (int off = 1; off < 64; off <<= 1)
                part[p] += __shfl_xor(part[p], off);
        }
        if (lane < 4) {
            int pt = 4 * t + lane;
            if (pt < 127) {
                int aa = (i + 1 + pt) & 127;
                float vv = (lane == 0) ? part[0] : (lane == 1) ? part[1] : (lane == 2) ? part[2] : part[3];
                srow[aa] = vv;
            }
        }
    }
}

__global__ __launch_bounds__(256) void k_force(
    const float* __restrict__ xs, const float* __restrict__ dws,
    const float* __restrict__ S, float* __restrict__ Fr)
{
    int tid = threadIdx.x;
    int wave = tid >> 6, lane = tid & 63;
    int atom = blockIdx.x * 4 + wave;
    int b = atom >> 7, i = atom & 127;
    const float* xb = xs + b * (NN * 3);
    float xi0 = xb[i*3], xi1 = xb[i*3+1], xi2 = xb[i*3+2];
    const float* drow = dws + (atom << 7);
    const float* srow = S + (atom << 7);
    float fx = 0.f, fy = 0.f, fz = 0.f;
    for (int it = lane; it < 127; it += 64) {
        int aa = (i + 1 + it) & 127;
        float s = srow[aa] + S[(((b << 7) + aa) << 7) + i];
        float coef = s / drow[aa];
        fx += coef * (xi0 - xb[aa*3]);
        fy += coef * (xi1 - xb[aa*3+1]);
        fz += coef * (xi2 - xb[aa*3+2]);
    }
    #pragma unroll
    for (int off = 1; off < 64; off <<= 1) {
        fx += __shfl_xor(fx, off);
        fy += __shfl_xor(fy, off);
        fz += __shfl_xor(fz, off);
    }
    if (lane == 0) {
        Fr[atom*3]   = fx;
        Fr[atom*3+1] = fy;
        Fr[atom*3+2] = fz;
    }
}

__global__ __launch_bounds__(128) void k_out(const float* __restrict__ Fr, float* __restrict__ out)
{
    __shared__ float rs[3][128];
    int b = blockIdx.x, n = threadIdx.x;
    float g0 = Fr[(b*128+n)*3], g1 = Fr[(b*128+n)*3+1], g2 = Fr[(b*128+n)*3+2];
    rs[0][n] = g0; rs[1][n] = g1; rs[2][n] = g2;
    __syncthreads();
    for (int s = 64; s > 0; s >>= 1) {
        if (n < s) {
            rs[0][n] += rs[0][n+s];
            rs[1][n] += rs[1][n+s];
            rs[2][n] += rs[2][n+s];
        }
        __syncthreads();
    }
    float m0 = rs[0][0] * (1.f/128.f);
    float m1 = rs[1][0] * (1.f/128.f);
    float m2 = rs[2][0] * (1.f/128.f);
    out[b*384 + n*3 + 0] = m0 - g0;
    out[b*384 + n*3 + 1] = m1 - g1;
    out[b*384 + n*3 + 2] = m2 - g2;
}

extern "C" void kernel_launch(void* const* d_in, const int* in_sizes, int n_in,
                              void* d_out, int out_size, void* d_ws, size_t ws_size,
                              hipStream_t stream)
{
    const float* xs   = (const float*)d_in[1];
    const float* mus  = (const float*)d_in[2];
    const float* gam  = (const float*)d_in[3];
    const float* Wenc = (const float*)d_in[4];
    const float* benc = (const float*)d_in[5];
    const float* W1a  = (const float*)d_in[6];
    const float* b1a  = (const float*)d_in[7];
    const float* W2a  = (const float*)d_in[8];
    const float* b2a  = (const float*)d_in[9];
    const float* W1b  = (const float*)d_in[10];
    const float* b1b  = (const float*)d_in[11];
    const float* W2b  = (const float*)d_in[12];
    const float* b2b  = (const float*)d_in[13];
    const float* W1c  = (const float*)d_in[14];
    const float* b1c  = (const float*)d_in[15];
    const float* W2c  = (const float*)d_in[16];
    const float* b2c  = (const float*)d_in[17];
    const float* Wt1  = (const float*)d_in[18];
    const float* bt1  = (const float*)d_in[19];
    const float* Wt2  = (const float*)d_in[20];

    float* ws  = (float*)d_ws;
    float* dws = ws;
    float* S   = ws + 524288;
    float* P   = ws + 1048576;
    float* C   = ws + 2097152;
    float* Fr  = ws + 2883584;
    float* out = (float*)d_out;

    k_dist <<<2048, 256, 0, stream>>>(xs, dws);
    k_fwd  <<<1024, 256, 0, stream>>>(dws, mus, gam, W1a, W1b, W1c, b1a, b1b, b1c,
                                      W2a, W2b, W2c, b2a, b2b, b2c, Wenc, benc,
                                      Wt1, bt1, Wt2, P);
    k_atom <<<64, 256, 0, stream>>>(Wt1, W2a, W2b, W2c, P, C);
    k_bwd  <<<1024, 256, 0, stream>>>(dws, mus, gam, W1a, W1b, W1c, b1a, b1b, b1c, C, S);
    k_force<<<1024, 256, 0, stream>>>(xs, dws, S, Fr);
    k_out  <<<32, 128, 0, stream>>>(Fr, out);
}

// Round 3
// 948.384 us; speedup vs baseline: 1.2504x; 1.2504x over previous
//
#include <hip/hip_runtime.h>
#include <math.h>

#define NN 128
#define FF 64
#define KK 50
#define EPSV 1e-6f

// ws layout (floats):
// dws: [B*N*N]      off 0         (524288)
// S:   [B*N*N]      off 524288
// P:   [B*N*4*64]   off 1048576   (g, p1, p2, p3 per atom)
// C:   [B*N*3*64]   off 2097152
// Fr:  [B*N*3]      off 2883584

__device__ __forceinline__ float softplusf(float z) {
    float e = expf(-fabsf(z));
    float l = log1pf(e);
    return (z > 0.f) ? z + l : l;
}

__global__ __launch_bounds__(256) void k_dist(const float* __restrict__ xs, float* __restrict__ dws)
{
    int tid = blockIdx.x * 256 + threadIdx.x;
    int b = tid >> 14;
    int rem = tid & 16383;
    int i = rem >> 7, a = rem & 127;
    const float* xb = xs + b * (NN * 3);
    float dx = xb[i*3+0] - xb[a*3+0];
    float dy = xb[i*3+1] - xb[a*3+1];
    float dz = xb[i*3+2] - xb[a*3+2];
    dws[tid] = sqrtf(dx*dx + dy*dy + dz*dz + EPSV);
}

// ---------------- forward: P=16 pair tile, float4-packed LDS ----------------
__global__ __launch_bounds__(256) void k_fwd(
    const float* __restrict__ dws,
    const float* __restrict__ mus, const float* __restrict__ gamma,
    const float* __restrict__ W1a, const float* __restrict__ W1b, const float* __restrict__ W1c,
    const float* __restrict__ b1a, const float* __restrict__ b1b, const float* __restrict__ b1c,
    const float* __restrict__ W2a, const float* __restrict__ W2b, const float* __restrict__ W2c,
    const float* __restrict__ b2a, const float* __restrict__ b2b, const float* __restrict__ b2c,
    const float* __restrict__ Wenc, const float* __restrict__ benc,
    const float* __restrict__ Wt1, const float* __restrict__ bt1, const float* __restrict__ Wt2,
    float* __restrict__ Pout)
{
    __shared__ float4 w4[KK * FF];        // (wa,wb,wc,0)  51200 B
    __shared__ float  rbfs[4][KK][16];    // per-wave [k][p] 12800 B
    __shared__ float  dsh[4][16];
    __shared__ float  mus_s[KK];
    __shared__ double epid[4][FF];

    int tid = threadIdx.x;
    for (int idx = tid; idx < KK * FF; idx += 256)
        w4[idx] = make_float4(W1a[idx], W1b[idx], W1c[idx], 0.f);
    if (tid < KK) mus_s[tid] = mus[tid];
    __syncthreads();

    int wave = tid >> 6, lane = tid & 63, f = lane;
    int atom = blockIdx.x * 4 + wave;
    int i = atom & 127;
    float gam = gamma[0];
    float bb0 = b1a[f], bb1 = b1b[f], bb2 = b1c[f];
    double us0 = 0.0, us1 = 0.0, us2 = 0.0;
    const float* drow = dws + (atom << 7);

    for (int t = 0; t < 8; ++t) {
        if (lane < 16) {
            int aa = (i + 1 + 16 * t + lane) & 127;
            dsh[wave][lane] = drow[aa];
        }
        // fill this wave's rbf tile: 50*16 = 800 values
        #pragma unroll
        for (int pass = 0; pass < 13; ++pass) {
            int idx = lane + (pass << 6);
            if (idx < KK * 16) {
                int k = idx >> 4, p = idx & 15;
                float dd = dsh[wave][p] - mus_s[k];
                rbfs[wave][k][p] = expf(-gam * dd * dd);
            }
        }
        float z0[16], z1[16], z2[16];
        #pragma unroll
        for (int p = 0; p < 16; ++p) { z0[p] = bb0; z1[p] = bb1; z2[p] = bb2; }
        #pragma unroll 2
        for (int k = 0; k < KK; ++k) {
            float4 wv = w4[(k << 6) + f];
            float rr[16];
            {
                const float4* rp4 = (const float4*)(&rbfs[wave][k][0]);
                float4 a0 = rp4[0], a1 = rp4[1], a2 = rp4[2], a3 = rp4[3];
                *(float4*)&rr[0]  = a0; *(float4*)&rr[4]  = a1;
                *(float4*)&rr[8]  = a2; *(float4*)&rr[12] = a3;
            }
            #pragma unroll
            for (int p = 0; p < 16; ++p) {
                z0[p] = fmaf(rr[p], wv.x, z0[p]);
                z1[p] = fmaf(rr[p], wv.y, z1[p]);
                z2[p] = fmaf(rr[p], wv.z, z2[p]);
            }
        }
        int base = 16 * t;
        #pragma unroll
        for (int p = 0; p < 16; ++p) {
            if (base + p < 127) {
                us0 += (double)softplusf(z0[p]);
                us1 += (double)softplusf(z1[p]);
                us2 += (double)softplusf(z2[p]);
            }
        }
    }

    // per-atom epilogue (wave-local, double precision)
    double wf0, wf1, wf2;
    {
        epid[wave][lane] = us0;
        double acc = 0.0;
        for (int m = 0; m < 64; ++m) acc += epid[wave][m] * (double)W2a[m*64 + f];
        wf0 = 1.0 + acc + 127.0 * (double)b2a[f];

        epid[wave][lane] = us1;
        double acc1 = 0.0;
        for (int m = 0; m < 64; ++m) acc1 += epid[wave][m] * (double)W2b[m*64 + f];
        wf1 = 1.0 + acc1 + 127.0 * (double)b2b[f];

        epid[wave][lane] = us2;
        double acc2 = 0.0;
        for (int m = 0; m < 64; ++m) acc2 += epid[wave][m] * (double)W2c[m*64 + f];
        wf2 = 1.0 + acc2 + 127.0 * (double)b2c[f];
    }
    double h0 = (double)Wenc[f] + (double)benc[f];
    double h  = h0 * wf0 * wf1 * wf2;
    epid[wave][lane] = h;
    double pre = (double)bt1[lane];
    for (int m = 0; m < 64; ++m) pre += epid[wave][m] * (double)Wt1[m*64 + lane];
    double tv = tanh(pre);
    double gv = (1.0 - tv * tv) * (double)Wt2[lane];

    float* po = Pout + atom * 256;
    po[lane]       = (float)gv;
    po[64 + lane]  = (float)(h0 * wf1 * wf2);
    po[128 + lane] = (float)(h0 * wf0 * wf2);
    po[192 + lane] = (float)(h0 * wf0 * wf1);
}

// per-atom GEMM-ish: dvdh = g @ Wt1^T ; q_l = dvdh * p_l ; c_l = W2_l @ q_l
__global__ __launch_bounds__(256) void k_atom(
    const float* __restrict__ Wt1,
    const float* __restrict__ W2a, const float* __restrict__ W2b, const float* __restrict__ W2c,
    const float* __restrict__ P, float* __restrict__ C)
{
    __shared__ float L[64 * 65];
    __shared__ float W[64 * 65];
    __shared__ float tmp[4][64];
    int tid = threadIdx.x;
    for (int idx = tid; idx < 4096; idx += 256) {
        int r = idx >> 6, c = idx & 63;
        L[c * 65 + r] = Wt1[idx];
    }
    __syncthreads();
    int wave = tid >> 6, lane = tid & 63;
    float dv[16];
    #pragma unroll
    for (int rep = 0; rep < 16; ++rep) {
        int atom = blockIdx.x * 64 + rep * 4 + wave;
        float gval = P[atom * 256 + lane];
        tmp[wave][lane] = gval;
        float acc = 0.f;
        for (int m = 0; m < 64; ++m) acc = fmaf(tmp[wave][m], L[m * 65 + lane], acc);
        dv[rep] = acc;
    }
    const float* W2p[3] = { W2a, W2b, W2c };
    for (int l = 0; l < 3; ++l) {
        __syncthreads();
        for (int idx = tid; idx < 4096; idx += 256) {
            int r = idx >> 6, c = idx & 63;
            W[c * 65 + r] = W2p[l][idx];
        }
        __syncthreads();
        #pragma unroll
        for (int rep = 0; rep < 16; ++rep) {
            int atom = blockIdx.x * 64 + rep * 4 + wave;
            float q = dv[rep] * P[atom * 256 + 64 + l * 64 + lane];
            tmp[wave][lane] = q;
            float acc = 0.f;
            for (int m = 0; m < 64; ++m) acc = fmaf(tmp[wave][m], W[m * 65 + lane], acc);
            C[atom * 192 + l * 64 + lane] = acc;
        }
    }
}

// ---------------- backward: P=16 pair tile, float4-packed LDS ----------------
__global__ __launch_bounds__(256) void k_bwd(
    const float* __restrict__ dws,
    const float* __restrict__ mus, const float* __restrict__ gamma,
    const float* __restrict__ W1a, const float* __restrict__ W1b, const float* __restrict__ W1c,
    const float* __restrict__ b1a, const float* __restrict__ b1b, const float* __restrict__ b1c,
    const float* __restrict__ C, float* __restrict__ S)
{
    __shared__ float4 w4[KK * FF];        // 51200 B
    __shared__ float  rbfs[4][KK][16];    // 12800 B
    __shared__ float  rhos[4][KK][16];    // 12800 B
    __shared__ float  dsh[4][16];
    __shared__ float  mus_s[KK];

    int tid = threadIdx.x;
    for (int idx = tid; idx < KK * FF; idx += 256)
        w4[idx] = make_float4(W1a[idx], W1b[idx], W1c[idx], 0.f);
    if (tid < KK) mus_s[tid] = mus[tid];
    __syncthreads();

    int wave = tid >> 6, lane = tid & 63, f = lane;
    int atom = blockIdx.x * 4 + wave;
    int i = atom & 127;
    float gam = gamma[0];
    float c0 = C[atom*192 + f], c1 = C[atom*192 + 64 + f], c2 = C[atom*192 + 128 + f];
    float bb0 = b1a[f], bb1 = b1b[f], bb2 = b1c[f];
    const float* drow = dws + (atom << 7);
    float* srow = S + (atom << 7);

    for (int t = 0; t < 8; ++t) {
        if (lane < 16) {
            int aa = (i + 1 + 16 * t + lane) & 127;
            dsh[wave][lane] = drow[aa];
        }
        #pragma unroll
        for (int pass = 0; pass < 13; ++pass) {
            int idx = lane + (pass << 6);
            if (idx < KK * 16) {
                int k = idx >> 4, p = idx & 15;
                float dd = dsh[wave][p] - mus_s[k];
                float e = expf(-gam * dd * dd);
                rbfs[wave][k][p] = e;
                rhos[wave][k][p] = -2.f * gam * dd * e;
            }
        }
        float z0[16], z1[16], z2[16], y0[16], y1[16], y2[16];
        #pragma unroll
        for (int p = 0; p < 16; ++p) {
            z0[p] = bb0; z1[p] = bb1; z2[p] = bb2;
            y0[p] = 0.f; y1[p] = 0.f; y2[p] = 0.f;
        }
        for (int k = 0; k < KK; ++k) {
            float4 wv = w4[(k << 6) + f];
            float rr[16], qq[16];
            {
                const float4* rp4 = (const float4*)(&rbfs[wave][k][0]);
                float4 a0 = rp4[0], a1 = rp4[1], a2 = rp4[2], a3 = rp4[3];
                *(float4*)&rr[0]  = a0; *(float4*)&rr[4]  = a1;
                *(float4*)&rr[8]  = a2; *(float4*)&rr[12] = a3;
                const float4* qp4 = (const float4*)(&rhos[wave][k][0]);
                float4 b0v = qp4[0], b1v = qp4[1], b2v = qp4[2], b3v = qp4[3];
                *(float4*)&qq[0]  = b0v; *(float4*)&qq[4]  = b1v;
                *(float4*)&qq[8]  = b2v; *(float4*)&qq[12] = b3v;
            }
            #pragma unroll
            for (int p = 0; p < 16; ++p) {
                z0[p] = fmaf(rr[p], wv.x, z0[p]);
                z1[p] = fmaf(rr[p], wv.y, z1[p]);
                z2[p] = fmaf(rr[p], wv.z, z2[p]);
                y0[p] = fmaf(qq[p], wv.x, y0[p]);
                y1[p] = fmaf(qq[p], wv.y, y1[p]);
                y2[p] = fmaf(qq[p], wv.z, y2[p]);
            }
        }
        float part[16];
        #pragma unroll
        for (int p = 0; p < 16; ++p) {
            float s0 = 1.f / (1.f + expf(-z0[p]));
            float s1 = 1.f / (1.f + expf(-z1[p]));
            float s2 = 1.f / (1.f + expf(-z2[p]));
            part[p] = c0 * s0 * y0[p] + c1 * s1 * y1[p] + c2 * s2 * y2[p];
        }
        float outv = 0.f;
        #pragma unroll
        for (int p = 0; p < 16; ++p) {
            float v = part[p];
            #pragma unroll
            for (int off = 1; off < 64; off <<= 1) v += __shfl_xor(v, off);
            if (lane == p) outv = v;
        }
        if (lane < 16) {
            int pt = 16 * t + lane;
            if (pt < 127) srow[(i + 1 + pt) & 127] = outv;
        }
    }
}

__global__ __launch_bounds__(256) void k_force(
    const float* __restrict__ xs, const float* __restrict__ dws,
    const float* __restrict__ S, float* __restrict__ Fr)
{
    int tid = threadIdx.x;
    int wave = tid >> 6, lane = tid & 63;
    int atom = blockIdx.x * 4 + wave;
    int b = atom >> 7, i = atom & 127;
    const float* xb = xs + b * (NN * 3);
    float xi0 = xb[i*3], xi1 = xb[i*3+1], xi2 = xb[i*3+2];
    const float* drow = dws + (atom << 7);
    const float* srow = S + (atom << 7);
    float fx = 0.f, fy = 0.f, fz = 0.f;
    for (int it = lane; it < 127; it += 64) {
        int aa = (i + 1 + it) & 127;
        float s = srow[aa] + S[(((b << 7) + aa) << 7) + i];
        float coef = s / drow[aa];
        fx += coef * (xi0 - xb[aa*3]);
        fy += coef * (xi1 - xb[aa*3+1]);
        fz += coef * (xi2 - xb[aa*3+2]);
    }
    #pragma unroll
    for (int off = 1; off < 64; off <<= 1) {
        fx += __shfl_xor(fx, off);
        fy += __shfl_xor(fy, off);
        fz += __shfl_xor(fz, off);
    }
    if (lane == 0) {
        Fr[atom*3]   = fx;
        Fr[atom*3+1] = fy;
        Fr[atom*3+2] = fz;
    }
}

__global__ __launch_bounds__(128) void k_out(const float* __restrict__ Fr, float* __restrict__ out)
{
    __shared__ float rs[3][128];
    int b = blockIdx.x, n = threadIdx.x;
    float g0 = Fr[(b*128+n)*3], g1 = Fr[(b*128+n)*3+1], g2 = Fr[(b*128+n)*3+2];
    rs[0][n] = g0; rs[1][n] = g1; rs[2][n] = g2;
    __syncthreads();
    for (int s = 64; s > 0; s >>= 1) {
        if (n < s) {
            rs[0][n] += rs[0][n+s];
            rs[1][n] += rs[1][n+s];
            rs[2][n] += rs[2][n+s];
        }
        __syncthreads();
    }
    float m0 = rs[0][0] * (1.f/128.f);
    float m1 = rs[1][0] * (1.f/128.f);
    float m2 = rs[2][0] * (1.f/128.f);
    out[b*384 + n*3 + 0] = m0 - g0;
    out[b*384 + n*3 + 1] = m1 - g1;
    out[b*384 + n*3 + 2] = m2 - g2;
}

extern "C" void kernel_launch(void* const* d_in, const int* in_sizes, int n_in,
                              void* d_out, int out_size, void* d_ws, size_t ws_size,
                              hipStream_t stream)
{
    const float* xs   = (const float*)d_in[1];
    const float* mus  = (const float*)d_in[2];
    const float* gam  = (const float*)d_in[3];
    const float* Wenc = (const float*)d_in[4];
    const float* benc = (const float*)d_in[5];
    const float* W1a  = (const float*)d_in[6];
    const float* b1a  = (const float*)d_in[7];
    const float* W2a  = (const float*)d_in[8];
    const float* b2a  = (const float*)d_in[9];
    const float* W1b  = (const float*)d_in[10];
    const float* b1b  = (const float*)d_in[11];
    const float* W2b  = (const float*)d_in[12];
    const float* b2b  = (const float*)d_in[13];
    const float* W1c  = (const float*)d_in[14];
    const float* b1c  = (const float*)d_in[15];
    const float* W2c  = (const float*)d_in[16];
    const float* b2c  = (const float*)d_in[17];
    const float* Wt1  = (const float*)d_in[18];
    const float* bt1  = (const float*)d_in[19];
    const float* Wt2  = (const float*)d_in[20];

    float* ws  = (float*)d_ws;
    float* dws = ws;
    float* S   = ws + 524288;
    float* P   = ws + 1048576;
    float* C   = ws + 2097152;
    float* Fr  = ws + 2883584;
    float* out = (float*)d_out;

    k_dist <<<2048, 256, 0, stream>>>(xs, dws);
    k_fwd  <<<1024, 256, 0, stream>>>(dws, mus, gam, W1a, W1b, W1c, b1a, b1b, b1c,
                                      W2a, W2b, W2c, b2a, b2b, b2c, Wenc, benc,
                                      Wt1, bt1, Wt2, P);
    k_atom <<<64, 256, 0, stream>>>(Wt1, W2a, W2b, W2c, P, C);
    k_bwd  <<<1024, 256, 0, stream>>>(dws, mus, gam, W1a, W1b, W1c, b1a, b1b, b1c, C, S);
    k_force<<<1024, 256, 0, stream>>>(xs, dws, S, Fr);
    k_out  <<<32, 128, 0, stream>>>(Fr, out);
}

// Round 4
// 503.778 us; speedup vs baseline: 2.3540x; 1.8825x over previous
//
#include <hip/hip_runtime.h>
#include <math.h>

#define NN 128
#define FF 64
#define KK 50
#define EPSV 1e-6f

// ws layout (floats):
// dws: [B*N*N]      off 0         (524288)
// S:   [B*N*N]      off 524288
// C:   [B*N*3*64]   off 2097152
// Fr:  [B*N*3]      off 2883584

__device__ __forceinline__ float softplus_fast(float z) {
    float e = __expf(-fabsf(z));
    float l = __logf(1.f + e);
    return fmaxf(z, 0.f) + l;
}

__global__ __launch_bounds__(256) void k_dist(const float* __restrict__ xs, float* __restrict__ dws)
{
    int tid = blockIdx.x * 256 + threadIdx.x;
    int b = tid >> 14;
    int rem = tid & 16383;
    int i = rem >> 7, a = rem & 127;
    const float* xb = xs + b * (NN * 3);
    float dx = xb[i*3+0] - xb[a*3+0];
    float dy = xb[i*3+1] - xb[a*3+1];
    float dz = xb[i*3+2] - xb[a*3+2];
    dws[tid] = sqrtf(dx*dx + dy*dy + dz*dz + EPSV);
}

// ---------------- forward (+ fused per-atom k_atom): writes C ----------------
__global__ __launch_bounds__(256) void k_fwd(
    const float* __restrict__ dws,
    const float* __restrict__ mus, const float* __restrict__ gamma,
    const float* __restrict__ W1a, const float* __restrict__ W1b, const float* __restrict__ W1c,
    const float* __restrict__ b1a, const float* __restrict__ b1b, const float* __restrict__ b1c,
    const float* __restrict__ W2a, const float* __restrict__ W2b, const float* __restrict__ W2c,
    const float* __restrict__ b2a, const float* __restrict__ b2b, const float* __restrict__ b2c,
    const float* __restrict__ Wenc, const float* __restrict__ benc,
    const float* __restrict__ Wt1, const float* __restrict__ bt1, const float* __restrict__ Wt2,
    float* __restrict__ Cout)
{
    __shared__ float4 w4[KK * FF];        // (wa,wb,wc,0)  51200 B
    __shared__ float  rbfs[4][KK][16];    // per-wave [k][p] 12800 B
    __shared__ float  dsh[4][16];
    __shared__ float  mus_s[KK];
    __shared__ double epid[4][FF];
    __shared__ float  epif[4][FF];

    int tid = threadIdx.x;
    for (int idx = tid; idx < KK * FF; idx += 256)
        w4[idx] = make_float4(W1a[idx], W1b[idx], W1c[idx], 0.f);
    if (tid < KK) mus_s[tid] = mus[tid];
    __syncthreads();

    int wave = tid >> 6, lane = tid & 63, f = lane;
    int atom = blockIdx.x * 4 + wave;
    int i = atom & 127;
    float gam = gamma[0];
    float bb0 = b1a[f], bb1 = b1b[f], bb2 = b1c[f];
    double us0 = 0.0, us1 = 0.0, us2 = 0.0;
    const float* drow = dws + (atom << 7);

    for (int t = 0; t < 8; ++t) {
        if (lane < 16) {
            int aa = (i + 1 + 16 * t + lane) & 127;
            dsh[wave][lane] = drow[aa];
        }
        #pragma unroll
        for (int pass = 0; pass < 13; ++pass) {
            int idx = lane + (pass << 6);
            if (idx < KK * 16) {
                int k = idx >> 4, p = idx & 15;
                float dd = dsh[wave][p] - mus_s[k];
                rbfs[wave][k][p] = __expf(-gam * dd * dd);
            }
        }
        float z0[16], z1[16], z2[16];
        #pragma unroll
        for (int p = 0; p < 16; ++p) { z0[p] = bb0; z1[p] = bb1; z2[p] = bb2; }
        #pragma unroll 2
        for (int k = 0; k < KK; ++k) {
            float4 wv = w4[(k << 6) + f];
            float rr[16];
            {
                const float4* rp4 = (const float4*)(&rbfs[wave][k][0]);
                float4 a0 = rp4[0], a1 = rp4[1], a2 = rp4[2], a3 = rp4[3];
                *(float4*)&rr[0]  = a0; *(float4*)&rr[4]  = a1;
                *(float4*)&rr[8]  = a2; *(float4*)&rr[12] = a3;
            }
            #pragma unroll
            for (int p = 0; p < 16; ++p) {
                z0[p] = fmaf(rr[p], wv.x, z0[p]);
                z1[p] = fmaf(rr[p], wv.y, z1[p]);
                z2[p] = fmaf(rr[p], wv.z, z2[p]);
            }
        }
        int base = 16 * t;
        #pragma unroll
        for (int p = 0; p < 16; ++p) {
            if (base + p < 127) {
                us0 += (double)softplus_fast(z0[p]);
                us1 += (double)softplus_fast(z1[p]);
                us2 += (double)softplus_fast(z2[p]);
            }
        }
    }

    // per-atom epilogue (wave-local, double precision for h/pre path)
    double wf0, wf1, wf2;
    {
        epid[wave][lane] = us0;
        double acc = 0.0;
        for (int m = 0; m < 64; ++m) acc += epid[wave][m] * (double)W2a[m*64 + f];
        wf0 = 1.0 + acc + 127.0 * (double)b2a[f];

        epid[wave][lane] = us1;
        double acc1 = 0.0;
        for (int m = 0; m < 64; ++m) acc1 += epid[wave][m] * (double)W2b[m*64 + f];
        wf1 = 1.0 + acc1 + 127.0 * (double)b2b[f];

        epid[wave][lane] = us2;
        double acc2 = 0.0;
        for (int m = 0; m < 64; ++m) acc2 += epid[wave][m] * (double)W2c[m*64 + f];
        wf2 = 1.0 + acc2 + 127.0 * (double)b2c[f];
    }
    double h0 = (double)Wenc[f] + (double)benc[f];
    double h  = h0 * wf0 * wf1 * wf2;
    epid[wave][lane] = h;
    double pre = (double)bt1[lane];
    for (int m = 0; m < 64; ++m) pre += epid[wave][m] * (double)Wt1[m*64 + lane];
    double tv = tanh(pre);
    float gv = (float)((1.0 - tv * tv) * (double)Wt2[lane]);

    float p1 = (float)(h0 * wf1 * wf2);   // pairs with layer a (c0)
    float p2 = (float)(h0 * wf0 * wf2);   // layer b
    float p3 = (float)(h0 * wf0 * wf1);   // layer c

    // fused k_atom: dv = g @ Wt1^T (dv[f] = sum_o g[o] Wt1[f,o])
    epif[wave][lane] = gv;
    float dv = 0.f;
    for (int m = 0; m < 64; ++m) dv = fmaf(epif[wave][m], Wt1[lane*64 + m], dv);

    float* co = Cout + atom * 192;
    epif[wave][lane] = dv * p1;
    float c0 = 0.f;
    for (int m = 0; m < 64; ++m) c0 = fmaf(epif[wave][m], W2a[lane*64 + m], c0);
    co[lane] = c0;

    epif[wave][lane] = dv * p2;
    float c1 = 0.f;
    for (int m = 0; m < 64; ++m) c1 = fmaf(epif[wave][m], W2b[lane*64 + m], c1);
    co[64 + lane] = c1;

    epif[wave][lane] = dv * p3;
    float c2 = 0.f;
    for (int m = 0; m < 64; ++m) c2 = fmaf(epif[wave][m], W2c[lane*64 + m], c2);
    co[128 + lane] = c2;
}

// ---------------- backward: P=16 pair tile, fast transcendentals ----------------
__global__ __launch_bounds__(256) void k_bwd(
    const float* __restrict__ dws,
    const float* __restrict__ mus, const float* __restrict__ gamma,
    const float* __restrict__ W1a, const float* __restrict__ W1b, const float* __restrict__ W1c,
    const float* __restrict__ b1a, const float* __restrict__ b1b, const float* __restrict__ b1c,
    const float* __restrict__ C, float* __restrict__ S)
{
    __shared__ float4 w4[KK * FF];        // 51200 B
    __shared__ float  rbfs[4][KK][16];    // 12800 B
    __shared__ float  rhos[4][KK][16];    // 12800 B
    __shared__ float  dsh[4][16];
    __shared__ float  mus_s[KK];

    int tid = threadIdx.x;
    for (int idx = tid; idx < KK * FF; idx += 256)
        w4[idx] = make_float4(W1a[idx], W1b[idx], W1c[idx], 0.f);
    if (tid < KK) mus_s[tid] = mus[tid];
    __syncthreads();

    int wave = tid >> 6, lane = tid & 63, f = lane;
    int atom = blockIdx.x * 4 + wave;
    int i = atom & 127;
    float gam = gamma[0];
    float c0 = C[atom*192 + f], c1 = C[atom*192 + 64 + f], c2 = C[atom*192 + 128 + f];
    float bb0 = b1a[f], bb1 = b1b[f], bb2 = b1c[f];
    const float* drow = dws + (atom << 7);
    float* srow = S + (atom << 7);

    for (int t = 0; t < 8; ++t) {
        if (lane < 16) {
            int aa = (i + 1 + 16 * t + lane) & 127;
            dsh[wave][lane] = drow[aa];
        }
        #pragma unroll
        for (int pass = 0; pass < 13; ++pass) {
            int idx = lane + (pass << 6);
            if (idx < KK * 16) {
                int k = idx >> 4, p = idx & 15;
                float dd = dsh[wave][p] - mus_s[k];
                float e = __expf(-gam * dd * dd);
                rbfs[wave][k][p] = e;
                rhos[wave][k][p] = -2.f * gam * dd * e;
            }
        }
        float z0[16], z1[16], z2[16], y0[16], y1[16], y2[16];
        #pragma unroll
        for (int p = 0; p < 16; ++p) {
            z0[p] = bb0; z1[p] = bb1; z2[p] = bb2;
            y0[p] = 0.f; y1[p] = 0.f; y2[p] = 0.f;
        }
        for (int k = 0; k < KK; ++k) {
            float4 wv = w4[(k << 6) + f];
            float rr[16], qq[16];
            {
                const float4* rp4 = (const float4*)(&rbfs[wave][k][0]);
                float4 a0 = rp4[0], a1 = rp4[1], a2 = rp4[2], a3 = rp4[3];
                *(float4*)&rr[0]  = a0; *(float4*)&rr[4]  = a1;
                *(float4*)&rr[8]  = a2; *(float4*)&rr[12] = a3;
                const float4* qp4 = (const float4*)(&rhos[wave][k][0]);
                float4 b0v = qp4[0], b1v = qp4[1], b2v = qp4[2], b3v = qp4[3];
                *(float4*)&qq[0]  = b0v; *(float4*)&qq[4]  = b1v;
                *(float4*)&qq[8]  = b2v; *(float4*)&qq[12] = b3v;
            }
            #pragma unroll
            for (int p = 0; p < 16; ++p) {
                z0[p] = fmaf(rr[p], wv.x, z0[p]);
                z1[p] = fmaf(rr[p], wv.y, z1[p]);
                z2[p] = fmaf(rr[p], wv.z, z2[p]);
                y0[p] = fmaf(qq[p], wv.x, y0[p]);
                y1[p] = fmaf(qq[p], wv.y, y1[p]);
                y2[p] = fmaf(qq[p], wv.z, y2[p]);
            }
        }
        float part[16];
        #pragma unroll
        for (int p = 0; p < 16; ++p) {
            float s0 = __builtin_amdgcn_rcpf(1.f + __expf(-z0[p]));
            float s1 = __builtin_amdgcn_rcpf(1.f + __expf(-z1[p]));
            float s2 = __builtin_amdgcn_rcpf(1.f + __expf(-z2[p]));
            part[p] = c0 * s0 * y0[p] + c1 * s1 * y1[p] + c2 * s2 * y2[p];
        }
        float outv = 0.f;
        #pragma unroll
        for (int p = 0; p < 16; ++p) {
            float v = part[p];
            #pragma unroll
            for (int off = 1; off < 64; off <<= 1) v += __shfl_xor(v, off);
            if (lane == p) outv = v;
        }
        if (lane < 16) {
            int pt = 16 * t + lane;
            if (pt < 127) srow[(i + 1 + pt) & 127] = outv;
        }
    }
}

__global__ __launch_bounds__(256) void k_force(
    const float* __restrict__ xs, const float* __restrict__ dws,
    const float* __restrict__ S, float* __restrict__ Fr)
{
    int tid = threadIdx.x;
    int wave = tid >> 6, lane = tid & 63;
    int atom = blockIdx.x * 4 + wave;
    int b = atom >> 7, i = atom & 127;
    const float* xb = xs + b * (NN * 3);
    float xi0 = xb[i*3], xi1 = xb[i*3+1], xi2 = xb[i*3+2];
    const float* drow = dws + (atom << 7);
    const float* srow = S + (atom << 7);
    float fx = 0.f, fy = 0.f, fz = 0.f;
    for (int it = lane; it < 127; it += 64) {
        int aa = (i + 1 + it) & 127;
        float s = srow[aa] + S[(((b << 7) + aa) << 7) + i];
        float coef = s / drow[aa];
        fx += coef * (xi0 - xb[aa*3]);
        fy += coef * (xi1 - xb[aa*3+1]);
        fz += coef * (xi2 - xb[aa*3+2]);
    }
    #pragma unroll
    for (int off = 1; off < 64; off <<= 1) {
        fx += __shfl_xor(fx, off);
        fy += __shfl_xor(fy, off);
        fz += __shfl_xor(fz, off);
    }
    if (lane == 0) {
        Fr[atom*3]   = fx;
        Fr[atom*3+1] = fy;
        Fr[atom*3+2] = fz;
    }
}

__global__ __launch_bounds__(128) void k_out(const float* __restrict__ Fr, float* __restrict__ out)
{
    __shared__ float rs[3][128];
    int b = blockIdx.x, n = threadIdx.x;
    float g0 = Fr[(b*128+n)*3], g1 = Fr[(b*128+n)*3+1], g2 = Fr[(b*128+n)*3+2];
    rs[0][n] = g0; rs[1][n] = g1; rs[2][n] = g2;
    __syncthreads();
    for (int s = 64; s > 0; s >>= 1) {
        if (n < s) {
            rs[0][n] += rs[0][n+s];
            rs[1][n] += rs[1][n+s];
            rs[2][n] += rs[2][n+s];
        }
        __syncthreads();
    }
    float m0 = rs[0][0] * (1.f/128.f);
    float m1 = rs[1][0] * (1.f/128.f);
    float m2 = rs[2][0] * (1.f/128.f);
    out[b*384 + n*3 + 0] = m0 - g0;
    out[b*384 + n*3 + 1] = m1 - g1;
    out[b*384 + n*3 + 2] = m2 - g2;
}

extern "C" void kernel_launch(void* const* d_in, const int* in_sizes, int n_in,
                              void* d_out, int out_size, void* d_ws, size_t ws_size,
                              hipStream_t stream)
{
    const float* xs   = (const float*)d_in[1];
    const float* mus  = (const float*)d_in[2];
    const float* gam  = (const float*)d_in[3];
    const float* Wenc = (const float*)d_in[4];
    const float* benc = (const float*)d_in[5];
    const float* W1a  = (const float*)d_in[6];
    const float* b1a  = (const float*)d_in[7];
    const float* W2a  = (const float*)d_in[8];
    const float* b2a  = (const float*)d_in[9];
    const float* W1b  = (const float*)d_in[10];
    const float* b1b  = (const float*)d_in[11];
    const float* W2b  = (const float*)d_in[12];
    const float* b2b  = (const float*)d_in[13];
    const float* W1c  = (const float*)d_in[14];
    const float* b1c  = (const float*)d_in[15];
    const float* W2c  = (const float*)d_in[16];
    const float* b2c  = (const float*)d_in[17];
    const float* Wt1  = (const float*)d_in[18];
    const float* bt1  = (const float*)d_in[19];
    const float* Wt2  = (const float*)d_in[20];

    float* ws  = (float*)d_ws;
    float* dws = ws;
    float* S   = ws + 524288;
    float* C   = ws + 2097152;
    float* Fr  = ws + 2883584;
    float* out = (float*)d_out;

    k_dist <<<2048, 256, 0, stream>>>(xs, dws);
    k_fwd  <<<1024, 256, 0, stream>>>(dws, mus, gam, W1a, W1b, W1c, b1a, b1b, b1c,
                                      W2a, W2b, W2c, b2a, b2b, b2c, Wenc, benc,
                                      Wt1, bt1, Wt2, C);
    k_bwd  <<<1024, 256, 0, stream>>>(dws, mus, gam, W1a, W1b, W1c, b1a, b1b, b1c, C, S);
    k_force<<<1024, 256, 0, stream>>>(xs, dws, S, Fr);
    k_out  <<<32, 128, 0, stream>>>(Fr, out);
}

// Round 5
// 448.954 us; speedup vs baseline: 2.6415x; 1.1221x over previous
//
#include <hip/hip_runtime.h>
#include <math.h>

#define NN 128
#define FF 64
#define KK 50
#define EPSV 1e-6f

// ws layout (floats):
// dws: [B*N*N]      off 0         (524288)
// S:   [B*N*N]      off 524288
// ST:  [B*N*N]      off 1048576   (S transposed within each batch)
// C:   [B*N*3*64]   off 2097152
// Fr:  [B*N*3]      off 2883584

__device__ __forceinline__ float softplus_fast(float z) {
    float e = __expf(-fabsf(z));
    float l = __logf(1.f + e);
    return fmaxf(z, 0.f) + l;
}

__global__ __launch_bounds__(256) void k_dist(const float* __restrict__ xs, float* __restrict__ dws)
{
    int tid = blockIdx.x * 256 + threadIdx.x;
    int b = tid >> 14;
    int rem = tid & 16383;
    int i = rem >> 7, a = rem & 127;
    const float* xb = xs + b * (NN * 3);
    float dx = xb[i*3+0] - xb[a*3+0];
    float dy = xb[i*3+1] - xb[a*3+1];
    float dz = xb[i*3+2] - xb[a*3+2];
    dws[tid] = sqrtf(dx*dx + dy*dy + dz*dz + EPSV);
}

// ------- forward (+ fused per-atom backward weights): 8 waves/block -------
__global__ __launch_bounds__(512, 4) void k_fwd(
    const float* __restrict__ dws,
    const float* __restrict__ mus, const float* __restrict__ gamma,
    const float* __restrict__ W1a, const float* __restrict__ W1b, const float* __restrict__ W1c,
    const float* __restrict__ b1a, const float* __restrict__ b1b, const float* __restrict__ b1c,
    const float* __restrict__ W2a, const float* __restrict__ W2b, const float* __restrict__ W2c,
    const float* __restrict__ b2a, const float* __restrict__ b2b, const float* __restrict__ b2c,
    const float* __restrict__ Wenc, const float* __restrict__ benc,
    const float* __restrict__ Wt1, const float* __restrict__ bt1, const float* __restrict__ Wt2,
    float* __restrict__ Cout)
{
    __shared__ float2 wab[KK * FF];       // (wa,wb)  25600 B
    __shared__ float  wcs[KK * FF];       // wc       12800 B
    __shared__ float  rbfs[8][KK][16];    // 25600 B
    __shared__ float  dsh[8][16];
    __shared__ float  mus_s[64];
    __shared__ double epid[8][FF];
    __shared__ float  epif[8][FF];

    int tid = threadIdx.x;
    for (int idx = tid; idx < KK * FF; idx += 512) {
        wab[idx] = make_float2(W1a[idx], W1b[idx]);
        wcs[idx] = W1c[idx];
    }
    if (tid < KK) mus_s[tid] = mus[tid];
    __syncthreads();

    int wave = tid >> 6, lane = tid & 63, f = lane;
    int atom = blockIdx.x * 8 + wave;
    int i = atom & 127;
    float gam = gamma[0];
    float bb0 = b1a[f], bb1 = b1b[f], bb2 = b1c[f];
    double us0 = 0.0, us1 = 0.0, us2 = 0.0;
    const float* drow = dws + (atom << 7);

    for (int t = 0; t < 8; ++t) {
        if (lane < 16) {
            int aa = (i + 1 + 16 * t + lane) & 127;
            dsh[wave][lane] = drow[aa];
        }
        #pragma unroll
        for (int pass = 0; pass < 13; ++pass) {
            int idx = lane + (pass << 6);
            int k = idx >> 4, p = idx & 15;
            if (k < KK) {
                float dd = dsh[wave][p] - mus_s[k];
                rbfs[wave][k][p] = __expf(-gam * dd * dd);
            }
        }
        float z0[16], z1[16], z2[16];
        #pragma unroll
        for (int p = 0; p < 16; ++p) { z0[p] = bb0; z1[p] = bb1; z2[p] = bb2; }
        #pragma unroll 2
        for (int k = 0; k < KK; ++k) {
            float2 wv = wab[(k << 6) + f];
            float  wc = wcs[(k << 6) + f];
            float rr[16];
            {
                const float4* rp4 = (const float4*)(&rbfs[wave][k][0]);
                float4 a0 = rp4[0], a1 = rp4[1], a2 = rp4[2], a3 = rp4[3];
                *(float4*)&rr[0]  = a0; *(float4*)&rr[4]  = a1;
                *(float4*)&rr[8]  = a2; *(float4*)&rr[12] = a3;
            }
            #pragma unroll
            for (int p = 0; p < 16; ++p) {
                z0[p] = fmaf(rr[p], wv.x, z0[p]);
                z1[p] = fmaf(rr[p], wv.y, z1[p]);
                z2[p] = fmaf(rr[p], wc,   z2[p]);
            }
        }
        int base = 16 * t;
        #pragma unroll
        for (int p = 0; p < 16; ++p) {
            if (base + p < 127) {
                us0 += (double)softplus_fast(z0[p]);
                us1 += (double)softplus_fast(z1[p]);
                us2 += (double)softplus_fast(z2[p]);
            }
        }
    }

    // per-atom epilogue (wave-local, double precision for h/pre path)
    double wf0, wf1, wf2;
    {
        epid[wave][lane] = us0;
        double acc = 0.0;
        for (int m = 0; m < 64; ++m) acc += epid[wave][m] * (double)W2a[m*64 + f];
        wf0 = 1.0 + acc + 127.0 * (double)b2a[f];

        epid[wave][lane] = us1;
        double acc1 = 0.0;
        for (int m = 0; m < 64; ++m) acc1 += epid[wave][m] * (double)W2b[m*64 + f];
        wf1 = 1.0 + acc1 + 127.0 * (double)b2b[f];

        epid[wave][lane] = us2;
        double acc2 = 0.0;
        for (int m = 0; m < 64; ++m) acc2 += epid[wave][m] * (double)W2c[m*64 + f];
        wf2 = 1.0 + acc2 + 127.0 * (double)b2c[f];
    }
    double h0 = (double)Wenc[f] + (double)benc[f];
    double h  = h0 * wf0 * wf1 * wf2;
    epid[wave][lane] = h;
    double pre = (double)bt1[lane];
    for (int m = 0; m < 64; ++m) pre += epid[wave][m] * (double)Wt1[m*64 + lane];
    double tv = tanh(pre);
    float gv = (float)((1.0 - tv * tv) * (double)Wt2[lane]);

    float p1 = (float)(h0 * wf1 * wf2);   // pairs with layer a (c0)
    float p2 = (float)(h0 * wf0 * wf2);   // layer b
    float p3 = (float)(h0 * wf0 * wf1);   // layer c

    // fused: dv = g @ Wt1^T (dv[f] = sum_o g[o] Wt1[f,o])
    epif[wave][lane] = gv;
    float dv = 0.f;
    for (int m = 0; m < 64; ++m) dv = fmaf(epif[wave][m], Wt1[lane*64 + m], dv);

    float* co = Cout + atom * 192;
    epif[wave][lane] = dv * p1;
    float c0 = 0.f;
    for (int m = 0; m < 64; ++m) c0 = fmaf(epif[wave][m], W2a[lane*64 + m], c0);
    co[lane] = c0;

    epif[wave][lane] = dv * p2;
    float c1 = 0.f;
    for (int m = 0; m < 64; ++m) c1 = fmaf(epif[wave][m], W2b[lane*64 + m], c1);
    co[64 + lane] = c1;

    epif[wave][lane] = dv * p3;
    float c2 = 0.f;
    for (int m = 0; m < 64; ++m) c2 = fmaf(epif[wave][m], W2c[lane*64 + m], c2);
    co[128 + lane] = c2;
}

// ---------------- backward: P=16 pair tile, fast transcendentals ----------------
__global__ __launch_bounds__(256) void k_bwd(
    const float* __restrict__ dws,
    const float* __restrict__ mus, const float* __restrict__ gamma,
    const float* __restrict__ W1a, const float* __restrict__ W1b, const float* __restrict__ W1c,
    const float* __restrict__ b1a, const float* __restrict__ b1b, const float* __restrict__ b1c,
    const float* __restrict__ C, float* __restrict__ S, float* __restrict__ ST)
{
    __shared__ float4 w4[KK * FF];        // 51200 B
    __shared__ float  rbfs[4][KK][16];    // 12800 B
    __shared__ float  rhos[4][KK][16];    // 12800 B
    __shared__ float  dsh[4][16];
    __shared__ float  mus_s[64];

    int tid = threadIdx.x;
    for (int idx = tid; idx < KK * FF; idx += 256)
        w4[idx] = make_float4(W1a[idx], W1b[idx], W1c[idx], 0.f);
    if (tid < KK) mus_s[tid] = mus[tid];
    __syncthreads();

    int wave = tid >> 6, lane = tid & 63, f = lane;
    int atom = blockIdx.x * 4 + wave;
    int b = atom >> 7, i = atom & 127;
    float gam = gamma[0];
    float c0 = C[atom*192 + f], c1 = C[atom*192 + 64 + f], c2 = C[atom*192 + 128 + f];
    float bb0 = b1a[f], bb1 = b1b[f], bb2 = b1c[f];
    const float* drow = dws + (atom << 7);
    float* srow = S + (atom << 7);

    for (int t = 0; t < 8; ++t) {
        if (lane < 16) {
            int aa = (i + 1 + 16 * t + lane) & 127;
            dsh[wave][lane] = drow[aa];
        }
        #pragma unroll
        for (int pass = 0; pass < 13; ++pass) {
            int idx = lane + (pass << 6);
            int k = idx >> 4, p = idx & 15;
            if (k < KK) {
                float dd = dsh[wave][p] - mus_s[k];
                float e = __expf(-gam * dd * dd);
                rbfs[wave][k][p] = e;
                rhos[wave][k][p] = -2.f * gam * dd * e;
            }
        }
        float z0[16], z1[16], z2[16], y0[16], y1[16], y2[16];
        #pragma unroll
        for (int p = 0; p < 16; ++p) {
            z0[p] = bb0; z1[p] = bb1; z2[p] = bb2;
            y0[p] = 0.f; y1[p] = 0.f; y2[p] = 0.f;
        }
        for (int k = 0; k < KK; ++k) {
            float4 wv = w4[(k << 6) + f];
            float rr[16], qq[16];
            {
                const float4* rp4 = (const float4*)(&rbfs[wave][k][0]);
                float4 a0 = rp4[0], a1 = rp4[1], a2 = rp4[2], a3 = rp4[3];
                *(float4*)&rr[0]  = a0; *(float4*)&rr[4]  = a1;
                *(float4*)&rr[8]  = a2; *(float4*)&rr[12] = a3;
                const float4* qp4 = (const float4*)(&rhos[wave][k][0]);
                float4 b0v = qp4[0], b1v = qp4[1], b2v = qp4[2], b3v = qp4[3];
                *(float4*)&qq[0]  = b0v; *(float4*)&qq[4]  = b1v;
                *(float4*)&qq[8]  = b2v; *(float4*)&qq[12] = b3v;
            }
            #pragma unroll
            for (int p = 0; p < 16; ++p) {
                z0[p] = fmaf(rr[p], wv.x, z0[p]);
                z1[p] = fmaf(rr[p], wv.y, z1[p]);
                z2[p] = fmaf(rr[p], wv.z, z2[p]);
                y0[p] = fmaf(qq[p], wv.x, y0[p]);
                y1[p] = fmaf(qq[p], wv.y, y1[p]);
                y2[p] = fmaf(qq[p], wv.z, y2[p]);
            }
        }
        float part[16];
        #pragma unroll
        for (int p = 0; p < 16; ++p) {
            float s0 = __builtin_amdgcn_rcpf(1.f + __expf(-z0[p]));
            float s1 = __builtin_amdgcn_rcpf(1.f + __expf(-z1[p]));
            float s2 = __builtin_amdgcn_rcpf(1.f + __expf(-z2[p]));
            part[p] = c0 * s0 * y0[p] + c1 * s1 * y1[p] + c2 * s2 * y2[p];
        }
        float outv = 0.f;
        #pragma unroll
        for (int p = 0; p < 16; ++p) {
            float v = part[p];
            #pragma unroll
            for (int off = 1; off < 64; off <<= 1) v += __shfl_xor(v, off);
            if (lane == p) outv = v;
        }
        if (lane < 16) {
            int pt = 16 * t + lane;
            if (pt < 127) {
                int aa = (i + 1 + pt) & 127;
                srow[aa] = outv;
                ST[(((b << 7) + aa) << 7) + i] = outv;   // transposed copy
            }
        }
    }
}

__global__ __launch_bounds__(256) void k_force(
    const float* __restrict__ xs, const float* __restrict__ dws,
    const float* __restrict__ S, const float* __restrict__ ST, float* __restrict__ Fr)
{
    int tid = threadIdx.x;
    int wave = tid >> 6, lane = tid & 63;
    int atom = blockIdx.x * 4 + wave;
    int b = atom >> 7, i = atom & 127;
    const float* xb = xs + b * (NN * 3);
    float xi0 = xb[i*3], xi1 = xb[i*3+1], xi2 = xb[i*3+2];
    const float* drow  = dws + (atom << 7);
    const float* srow  = S  + (atom << 7);
    const float* strow = ST + (atom << 7);
    float fx = 0.f, fy = 0.f, fz = 0.f;
    for (int it = lane; it < 127; it += 64) {
        int aa = (i + 1 + it) & 127;
        float s = srow[aa] + strow[aa];
        float coef = s / drow[aa];
        fx += coef * (xi0 - xb[aa*3]);
        fy += coef * (xi1 - xb[aa*3+1]);
        fz += coef * (xi2 - xb[aa*3+2]);
    }
    #pragma unroll
    for (int off = 1; off < 64; off <<= 1) {
        fx += __shfl_xor(fx, off);
        fy += __shfl_xor(fy, off);
        fz += __shfl_xor(fz, off);
    }
    if (lane == 0) {
        Fr[atom*3]   = fx;
        Fr[atom*3+1] = fy;
        Fr[atom*3+2] = fz;
    }
}

__global__ __launch_bounds__(128) void k_out(const float* __restrict__ Fr, float* __restrict__ out)
{
    __shared__ float rs[3][128];
    int b = blockIdx.x, n = threadIdx.x;
    float g0 = Fr[(b*128+n)*3], g1 = Fr[(b*128+n)*3+1], g2 = Fr[(b*128+n)*3+2];
    rs[0][n] = g0; rs[1][n] = g1; rs[2][n] = g2;
    __syncthreads();
    for (int s = 64; s > 0; s >>= 1) {
        if (n < s) {
            rs[0][n] += rs[0][n+s];
            rs[1][n] += rs[1][n+s];
            rs[2][n] += rs[2][n+s];
        }
        __syncthreads();
    }
    float m0 = rs[0][0] * (1.f/128.f);
    float m1 = rs[1][0] * (1.f/128.f);
    float m2 = rs[2][0] * (1.f/128.f);
    out[b*384 + n*3 + 0] = m0 - g0;
    out[b*384 + n*3 + 1] = m1 - g1;
    out[b*384 + n*3 + 2] = m2 - g2;
}

extern "C" void kernel_launch(void* const* d_in, const int* in_sizes, int n_in,
                              void* d_out, int out_size, void* d_ws, size_t ws_size,
                              hipStream_t stream)
{
    const float* xs   = (const float*)d_in[1];
    const float* mus  = (const float*)d_in[2];
    const float* gam  = (const float*)d_in[3];
    const float* Wenc = (const float*)d_in[4];
    const float* benc = (const float*)d_in[5];
    const float* W1a  = (const float*)d_in[6];
    const float* b1a  = (const float*)d_in[7];
    const float* W2a  = (const float*)d_in[8];
    const float* b2a  = (const float*)d_in[9];
    const float* W1b  = (const float*)d_in[10];
    const float* b1b  = (const float*)d_in[11];
    const float* W2b  = (const float*)d_in[12];
    const float* b2b  = (const float*)d_in[13];
    const float* W1c  = (const float*)d_in[14];
    const float* b1c  = (const float*)d_in[15];
    const float* W2c  = (const float*)d_in[16];
    const float* b2c  = (const float*)d_in[17];
    const float* Wt1  = (const float*)d_in[18];
    const float* bt1  = (const float*)d_in[19];
    const float* Wt2  = (const float*)d_in[20];

    float* ws  = (float*)d_ws;
    float* dws = ws;
    float* S   = ws + 524288;
    float* ST  = ws + 1048576;
    float* C   = ws + 2097152;
    float* Fr  = ws + 2883584;
    float* out = (float*)d_out;

    k_dist <<<2048, 256, 0, stream>>>(xs, dws);
    k_fwd  <<<512, 512, 0, stream>>>(dws, mus, gam, W1a, W1b, W1c, b1a, b1b, b1c,
                                     W2a, W2b, W2c, b2a, b2b, b2c, Wenc, benc,
                                     Wt1, bt1, Wt2, C);
    k_bwd  <<<1024, 256, 0, stream>>>(dws, mus, gam, W1a, W1b, W1c, b1a, b1b, b1c, C, S, ST);
    k_force<<<1024, 256, 0, stream>>>(xs, dws, S, ST, Fr);
    k_out  <<<32, 128, 0, stream>>>(Fr, out);
}

// Round 6
// 427.307 us; speedup vs baseline: 2.7753x; 1.0507x over previous
//
#include <hip/hip_runtime.h>
#include <math.h>

#define NN 128
#define FF 64
#define KK 50
#define EPSV 1e-6f

// ws layout (floats):
// dws: [B*N*N]      off 0         (524288)
// T:   [B*N*N]      off 524288    (s_ia + s_ai, both orderings filled)
// wT:  [3*64*50]    off 1048576   (W1 transposed: [l][f][k])
// C:   [B*N*3*64]   off 2097152
// Fr:  [B*N*3]      off 2883584

__device__ __forceinline__ float softplus_fast(float z) {
    float e = __expf(-fabsf(z));
    float l = __logf(1.f + e);
    return fmaxf(z, 0.f) + l;
}

__global__ __launch_bounds__(256) void k_dist(const float* __restrict__ xs, float* __restrict__ dws)
{
    int tid = blockIdx.x * 256 + threadIdx.x;
    int b = tid >> 14;
    int rem = tid & 16383;
    int i = rem >> 7, a = rem & 127;
    const float* xb = xs + b * (NN * 3);
    float dx = xb[i*3+0] - xb[a*3+0];
    float dy = xb[i*3+1] - xb[a*3+1];
    float dz = xb[i*3+2] - xb[a*3+2];
    dws[tid] = sqrtf(dx*dx + dy*dy + dz*dz + EPSV);
}

__global__ __launch_bounds__(256) void k_prep(
    const float* __restrict__ W1a, const float* __restrict__ W1b, const float* __restrict__ W1c,
    float* __restrict__ wT)
{
    int idx = blockIdx.x * 256 + threadIdx.x;   // 3*64*50 = 9600
    if (idx < 3 * FF * KK) {
        int l = idx / (FF * KK), r = idx - l * (FF * KK);
        int f = r / KK, k = r - f * KK;
        const float* W = (l == 0) ? W1a : (l == 1) ? W1b : W1c;
        wT[idx] = W[k * FF + f];
    }
}

// ------- forward (+ fused per-atom backward weights): 8 waves/block -------
__global__ __launch_bounds__(512, 4) void k_fwd(
    const float* __restrict__ dws,
    const float* __restrict__ mus, const float* __restrict__ gamma,
    const float* __restrict__ W1a, const float* __restrict__ W1b, const float* __restrict__ W1c,
    const float* __restrict__ b1a, const float* __restrict__ b1b, const float* __restrict__ b1c,
    const float* __restrict__ W2a, const float* __restrict__ W2b, const float* __restrict__ W2c,
    const float* __restrict__ b2a, const float* __restrict__ b2b, const float* __restrict__ b2c,
    const float* __restrict__ Wenc, const float* __restrict__ benc,
    const float* __restrict__ Wt1, const float* __restrict__ bt1, const float* __restrict__ Wt2,
    float* __restrict__ Cout)
{
    __shared__ float2 wab[KK * FF];       // (wa,wb)  25600 B
    __shared__ float  wcs[KK * FF];       // wc       12800 B
    __shared__ float  rbfs[8][KK][16];    // 25600 B
    __shared__ float  dsh[8][16];
    __shared__ float  mus_s[64];
    __shared__ double epid[8][FF];
    __shared__ float  epif[8][FF];

    int tid = threadIdx.x;
    for (int idx = tid; idx < KK * FF; idx += 512) {
        wab[idx] = make_float2(W1a[idx], W1b[idx]);
        wcs[idx] = W1c[idx];
    }
    if (tid < KK) mus_s[tid] = mus[tid];
    __syncthreads();

    int wave = tid >> 6, lane = tid & 63, f = lane;
    int atom = blockIdx.x * 8 + wave;
    int i = atom & 127;
    float gam = gamma[0];
    float bb0 = b1a[f], bb1 = b1b[f], bb2 = b1c[f];
    double us0 = 0.0, us1 = 0.0, us2 = 0.0;
    const float* drow = dws + (atom << 7);

    for (int t = 0; t < 8; ++t) {
        if (lane < 16) {
            int aa = (i + 1 + 16 * t + lane) & 127;
            dsh[wave][lane] = drow[aa];
        }
        #pragma unroll
        for (int pass = 0; pass < 13; ++pass) {
            int idx = lane + (pass << 6);
            int k = idx >> 4, p = idx & 15;
            if (k < KK) {
                float dd = dsh[wave][p] - mus_s[k];
                rbfs[wave][k][p] = __expf(-gam * dd * dd);
            }
        }
        float z0[16], z1[16], z2[16];
        #pragma unroll
        for (int p = 0; p < 16; ++p) { z0[p] = bb0; z1[p] = bb1; z2[p] = bb2; }
        #pragma unroll 2
        for (int k = 0; k < KK; ++k) {
            float2 wv = wab[(k << 6) + f];
            float  wc = wcs[(k << 6) + f];
            float rr[16];
            {
                const float4* rp4 = (const float4*)(&rbfs[wave][k][0]);
                float4 a0 = rp4[0], a1 = rp4[1], a2 = rp4[2], a3 = rp4[3];
                *(float4*)&rr[0]  = a0; *(float4*)&rr[4]  = a1;
                *(float4*)&rr[8]  = a2; *(float4*)&rr[12] = a3;
            }
            #pragma unroll
            for (int p = 0; p < 16; ++p) {
                z0[p] = fmaf(rr[p], wv.x, z0[p]);
                z1[p] = fmaf(rr[p], wv.y, z1[p]);
                z2[p] = fmaf(rr[p], wc,   z2[p]);
            }
        }
        int base = 16 * t;
        #pragma unroll
        for (int p = 0; p < 16; ++p) {
            if (base + p < 127) {
                us0 += (double)softplus_fast(z0[p]);
                us1 += (double)softplus_fast(z1[p]);
                us2 += (double)softplus_fast(z2[p]);
            }
        }
    }

    // per-atom epilogue (wave-local, double precision for h/pre path)
    double wf0, wf1, wf2;
    {
        epid[wave][lane] = us0;
        double acc = 0.0;
        for (int m = 0; m < 64; ++m) acc += epid[wave][m] * (double)W2a[m*64 + f];
        wf0 = 1.0 + acc + 127.0 * (double)b2a[f];

        epid[wave][lane] = us1;
        double acc1 = 0.0;
        for (int m = 0; m < 64; ++m) acc1 += epid[wave][m] * (double)W2b[m*64 + f];
        wf1 = 1.0 + acc1 + 127.0 * (double)b2b[f];

        epid[wave][lane] = us2;
        double acc2 = 0.0;
        for (int m = 0; m < 64; ++m) acc2 += epid[wave][m] * (double)W2c[m*64 + f];
        wf2 = 1.0 + acc2 + 127.0 * (double)b2c[f];
    }
    double h0 = (double)Wenc[f] + (double)benc[f];
    double h  = h0 * wf0 * wf1 * wf2;
    epid[wave][lane] = h;
    double pre = (double)bt1[lane];
    for (int m = 0; m < 64; ++m) pre += epid[wave][m] * (double)Wt1[m*64 + lane];
    double tv = tanh(pre);
    float gv = (float)((1.0 - tv * tv) * (double)Wt2[lane]);

    float p1 = (float)(h0 * wf1 * wf2);   // pairs with layer a
    float p2 = (float)(h0 * wf0 * wf2);   // layer b
    float p3 = (float)(h0 * wf0 * wf1);   // layer c

    // fused: dv = g @ Wt1^T
    epif[wave][lane] = gv;
    float dv = 0.f;
    for (int m = 0; m < 64; ++m) dv = fmaf(epif[wave][m], Wt1[lane*64 + m], dv);

    float* co = Cout + atom * 192;
    epif[wave][lane] = dv * p1;
    float c0 = 0.f;
    for (int m = 0; m < 64; ++m) c0 = fmaf(epif[wave][m], W2a[lane*64 + m], c0);
    co[lane] = c0;

    epif[wave][lane] = dv * p2;
    float c1 = 0.f;
    for (int m = 0; m < 64; ++m) c1 = fmaf(epif[wave][m], W2b[lane*64 + m], c1);
    co[64 + lane] = c1;

    epif[wave][lane] = dv * p3;
    float c2 = 0.f;
    for (int m = 0; m < 64; ++m) c2 = fmaf(epif[wave][m], W2c[lane*64 + m], c2);
    co[128 + lane] = c2;
}

// ------- backward: unordered pairs, lane=pair, rbf/rho in registers -------
// wave = one atom i; lanes 0..62 -> offsets 1..63; lane 63 -> offset 64 (valid iff i<64)
__global__ __launch_bounds__(256, 3) void k_bwd(
    const float* __restrict__ dws,
    const float* __restrict__ mus, const float* __restrict__ gamma,
    const float* __restrict__ wT,
    const float* __restrict__ b1a, const float* __restrict__ b1b, const float* __restrict__ b1c,
    const float* __restrict__ C, float* __restrict__ T)
{
    __shared__ float wsh[3 * FF * KK];    // 38400 B  [l][f][k]
    __shared__ float mus_s[64];

    int tid = threadIdx.x;
    for (int idx = tid; idx < 3 * FF * KK; idx += 256) wsh[idx] = wT[idx];
    if (tid < KK) mus_s[tid] = mus[tid];
    __syncthreads();

    int wave = tid >> 6, lane = tid & 63;
    int atom = blockIdx.x * 4 + wave;
    int b = atom >> 7, i = atom & 127;
    int off = lane + 1;                       // 1..64
    bool valid = (off < 64) || (i < 64);
    int a = (i + off) & 127;
    float gam = gamma[0];
    float d = dws[(atom << 7) + a];

    float rbf[KK], rho[KK];
    float n2g = -2.f * gam;
    #pragma unroll
    for (int k = 0; k < KK; ++k) {
        float dd = d - mus_s[k];
        float e = __expf(-gam * dd * dd);
        rbf[k] = e;
        rho[k] = n2g * dd * e;
    }

    const float* ci = C + atom * 192;
    const float* ca = C + (((b << 7) + a) * 192);
    float sia = 0.f, sai = 0.f;

    for (int f = 0; f < FF; ++f) {
        const float* wa = &wsh[f * KK];
        const float* wb = &wsh[FF * KK + f * KK];
        const float* wc = &wsh[2 * FF * KK + f * KK];
        float ca0 = ca[f], ca1 = ca[64 + f], ca2 = ca[128 + f];   // per-lane gather
        float z0 = 0.f, z1 = 0.f, z2 = 0.f, y0 = 0.f, y1 = 0.f, y2 = 0.f;
        #pragma unroll
        for (int k = 0; k < KK; ++k) {
            float r = rbf[k], q = rho[k];
            float w0 = wa[k], w1 = wb[k], w2 = wc[k];
            z0 = fmaf(r, w0, z0); y0 = fmaf(q, w0, y0);
            z1 = fmaf(r, w1, z1); y1 = fmaf(q, w1, y1);
            z2 = fmaf(r, w2, z2); y2 = fmaf(q, w2, y2);
        }
        z0 += b1a[f]; z1 += b1b[f]; z2 += b1c[f];
        float s0 = __builtin_amdgcn_rcpf(1.f + __expf(-z0));
        float s1 = __builtin_amdgcn_rcpf(1.f + __expf(-z1));
        float s2 = __builtin_amdgcn_rcpf(1.f + __expf(-z2));
        float g0 = s0 * y0, g1 = s1 * y1, g2 = s2 * y2;
        sia = fmaf(ci[f], g0, sia);
        sia = fmaf(ci[64 + f], g1, sia);
        sia = fmaf(ci[128 + f], g2, sia);
        sai = fmaf(ca0, g0, sai);
        sai = fmaf(ca1, g1, sai);
        sai = fmaf(ca2, g2, sai);
    }
    if (valid) {
        float v = sia + sai;
        float* Tb = T + ((size_t)b << 14);
        Tb[(i << 7) + a] = v;
        Tb[(a << 7) + i] = v;
    }
}

__global__ __launch_bounds__(256) void k_force(
    const float* __restrict__ xs, const float* __restrict__ dws,
    const float* __restrict__ T, float* __restrict__ Fr)
{
    int tid = threadIdx.x;
    int wave = tid >> 6, lane = tid & 63;
    int atom = blockIdx.x * 4 + wave;
    int i = atom & 127;
    int b = atom >> 7;
    const float* xb = xs + b * (NN * 3);
    float xi0 = xb[i*3], xi1 = xb[i*3+1], xi2 = xb[i*3+2];
    const float* drow = dws + (atom << 7);
    const float* trow = T + (atom << 7);
    float fx = 0.f, fy = 0.f, fz = 0.f;
    for (int it = lane; it < 127; it += 64) {
        int aa = (i + 1 + it) & 127;
        float coef = trow[aa] / drow[aa];
        fx += coef * (xi0 - xb[aa*3]);
        fy += coef * (xi1 - xb[aa*3+1]);
        fz += coef * (xi2 - xb[aa*3+2]);
    }
    #pragma unroll
    for (int off = 1; off < 64; off <<= 1) {
        fx += __shfl_xor(fx, off);
        fy += __shfl_xor(fy, off);
        fz += __shfl_xor(fz, off);
    }
    if (lane == 0) {
        Fr[atom*3]   = fx;
        Fr[atom*3+1] = fy;
        Fr[atom*3+2] = fz;
    }
}

__global__ __launch_bounds__(128) void k_out(const float* __restrict__ Fr, float* __restrict__ out)
{
    __shared__ float rs[3][128];
    int b = blockIdx.x, n = threadIdx.x;
    float g0 = Fr[(b*128+n)*3], g1 = Fr[(b*128+n)*3+1], g2 = Fr[(b*128+n)*3+2];
    rs[0][n] = g0; rs[1][n] = g1; rs[2][n] = g2;
    __syncthreads();
    for (int s = 64; s > 0; s >>= 1) {
        if (n < s) {
            rs[0][n] += rs[0][n+s];
            rs[1][n] += rs[1][n+s];
            rs[2][n] += rs[2][n+s];
        }
        __syncthreads();
    }
    float m0 = rs[0][0] * (1.f/128.f);
    float m1 = rs[1][0] * (1.f/128.f);
    float m2 = rs[2][0] * (1.f/128.f);
    out[b*384 + n*3 + 0] = m0 - g0;
    out[b*384 + n*3 + 1] = m1 - g1;
    out[b*384 + n*3 + 2] = m2 - g2;
}

extern "C" void kernel_launch(void* const* d_in, const int* in_sizes, int n_in,
                              void* d_out, int out_size, void* d_ws, size_t ws_size,
                              hipStream_t stream)
{
    const float* xs   = (const float*)d_in[1];
    const float* mus  = (const float*)d_in[2];
    const float* gam  = (const float*)d_in[3];
    const float* Wenc = (const float*)d_in[4];
    const float* benc = (const float*)d_in[5];
    const float* W1a  = (const float*)d_in[6];
    const float* b1a  = (const float*)d_in[7];
    const float* W2a  = (const float*)d_in[8];
    const float* b2a  = (const float*)d_in[9];
    const float* W1b  = (const float*)d_in[10];
    const float* b1b  = (const float*)d_in[11];
    const float* W2b  = (const float*)d_in[12];
    const float* b2b  = (const float*)d_in[13];
    const float* W1c  = (const float*)d_in[14];
    const float* b1c  = (const float*)d_in[15];
    const float* W2c  = (const float*)d_in[16];
    const float* b2c  = (const float*)d_in[17];
    const float* Wt1  = (const float*)d_in[18];
    const float* bt1  = (const float*)d_in[19];
    const float* Wt2  = (const float*)d_in[20];

    float* ws  = (float*)d_ws;
    float* dws = ws;
    float* T   = ws + 524288;
    float* wT  = ws + 1048576;
    float* C   = ws + 2097152;
    float* Fr  = ws + 2883584;
    float* out = (float*)d_out;

    k_dist <<<2048, 256, 0, stream>>>(xs, dws);
    k_prep <<<38, 256, 0, stream>>>(W1a, W1b, W1c, wT);
    k_fwd  <<<512, 512, 0, stream>>>(dws, mus, gam, W1a, W1b, W1c, b1a, b1b, b1c,
                                     W2a, W2b, W2c, b2a, b2b, b2c, Wenc, benc,
                                     Wt1, bt1, Wt2, C);
    k_bwd  <<<1024, 256, 0, stream>>>(dws, mus, gam, wT, b1a, b1b, b1c, C, T);
    k_force<<<1024, 256, 0, stream>>>(xs, dws, T, Fr);
    k_out  <<<32, 128, 0, stream>>>(Fr, out);
}

// Round 7
// 343.349 us; speedup vs baseline: 3.4539x; 1.2445x over previous
//
#include <hip/hip_runtime.h>
#include <math.h>

#define NN 128
#define FF 64
#define KK 50
#define PT 8
#define EPSV 1e-6f

// ws layout (floats):
// dws: [B*N*N]      off 0         (524288)
// T:   [B*N*N]      off 524288    (s_ia + s_ai, both orderings filled)
// wu:  [3*50*64*2]  off 1048576   (W1 and u=2*gamma*mu_k*W1, interleaved)
// C:   [B*N*3*64]   off 2097152
// Fr:  [B*N*3]      off 2883584

__device__ __forceinline__ float softplus_fast(float z) {
    float e = __expf(-fabsf(z));
    float l = __logf(1.f + e);
    return fmaxf(z, 0.f) + l;
}

__global__ __launch_bounds__(256) void k_dist(const float* __restrict__ xs, float* __restrict__ dws)
{
    int tid = blockIdx.x * 256 + threadIdx.x;
    int b = tid >> 14;
    int rem = tid & 16383;
    int i = rem >> 7, a = rem & 127;
    const float* xb = xs + b * (NN * 3);
    float dx = xb[i*3+0] - xb[a*3+0];
    float dy = xb[i*3+1] - xb[a*3+1];
    float dz = xb[i*3+2] - xb[a*3+2];
    dws[tid] = sqrtf(dx*dx + dy*dy + dz*dz + EPSV);
}

// build (w, u) pairs: u[l][k][f] = 2*gamma*mu_k * W1l[k][f]
__global__ __launch_bounds__(256) void k_prep(
    const float* __restrict__ W1a, const float* __restrict__ W1b, const float* __restrict__ W1c,
    const float* __restrict__ mus, const float* __restrict__ gamma,
    float2* __restrict__ wu)
{
    int idx = blockIdx.x * 256 + threadIdx.x;   // 3*50*64 = 9600
    if (idx < 3 * KK * FF) {
        int l = idx / (KK * FF), r = idx - l * (KK * FF);
        int k = r >> 6;
        const float* W = (l == 0) ? W1a : (l == 1) ? W1b : W1c;
        float w = W[r];
        wu[idx] = make_float2(w, 2.f * gamma[0] * mus[k] * w);
    }
}

// ------- forward (+ fused per-atom backward weights): 8 waves/block -------
__global__ __launch_bounds__(512, 4) void k_fwd(
    const float* __restrict__ dws,
    const float* __restrict__ mus, const float* __restrict__ gamma,
    const float* __restrict__ W1a, const float* __restrict__ W1b, const float* __restrict__ W1c,
    const float* __restrict__ b1a, const float* __restrict__ b1b, const float* __restrict__ b1c,
    const float* __restrict__ W2a, const float* __restrict__ W2b, const float* __restrict__ W2c,
    const float* __restrict__ b2a, const float* __restrict__ b2b, const float* __restrict__ b2c,
    const float* __restrict__ Wenc, const float* __restrict__ benc,
    const float* __restrict__ Wt1, const float* __restrict__ bt1, const float* __restrict__ Wt2,
    float* __restrict__ Cout)
{
    __shared__ float2 wab[KK * FF];       // (wa,wb)  25600 B
    __shared__ float  wcs[KK * FF];       // wc       12800 B
    __shared__ float  rbfs[8][KK][16];    // 25600 B
    __shared__ float  dsh[8][16];
    __shared__ float  mus_s[64];
    __shared__ double epid[8][FF];
    __shared__ float  epif[8][FF];

    int tid = threadIdx.x;
    for (int idx = tid; idx < KK * FF; idx += 512) {
        wab[idx] = make_float2(W1a[idx], W1b[idx]);
        wcs[idx] = W1c[idx];
    }
    if (tid < KK) mus_s[tid] = mus[tid];
    __syncthreads();

    int wave = tid >> 6, lane = tid & 63, f = lane;
    int atom = blockIdx.x * 8 + wave;
    int i = atom & 127;
    float gam = gamma[0];
    float bb0 = b1a[f], bb1 = b1b[f], bb2 = b1c[f];
    double us0 = 0.0, us1 = 0.0, us2 = 0.0;
    const float* drow = dws + (atom << 7);

    for (int t = 0; t < 8; ++t) {
        if (lane < 16) {
            int aa = (i + 1 + 16 * t + lane) & 127;
            dsh[wave][lane] = drow[aa];
        }
        #pragma unroll
        for (int pass = 0; pass < 13; ++pass) {
            int idx = lane + (pass << 6);
            int k = idx >> 4, p = idx & 15;
            if (k < KK) {
                float dd = dsh[wave][p] - mus_s[k];
                rbfs[wave][k][p] = __expf(-gam * dd * dd);
            }
        }
        float z0[16], z1[16], z2[16];
        #pragma unroll
        for (int p = 0; p < 16; ++p) { z0[p] = bb0; z1[p] = bb1; z2[p] = bb2; }
        #pragma unroll 2
        for (int k = 0; k < KK; ++k) {
            float2 wv = wab[(k << 6) + f];
            float  wc = wcs[(k << 6) + f];
            float rr[16];
            {
                const float4* rp4 = (const float4*)(&rbfs[wave][k][0]);
                float4 a0 = rp4[0], a1 = rp4[1], a2 = rp4[2], a3 = rp4[3];
                *(float4*)&rr[0]  = a0; *(float4*)&rr[4]  = a1;
                *(float4*)&rr[8]  = a2; *(float4*)&rr[12] = a3;
            }
            #pragma unroll
            for (int p = 0; p < 16; ++p) {
                z0[p] = fmaf(rr[p], wv.x, z0[p]);
                z1[p] = fmaf(rr[p], wv.y, z1[p]);
                z2[p] = fmaf(rr[p], wc,   z2[p]);
            }
        }
        int base = 16 * t;
        #pragma unroll
        for (int p = 0; p < 16; ++p) {
            if (base + p < 127) {
                us0 += (double)softplus_fast(z0[p]);
                us1 += (double)softplus_fast(z1[p]);
                us2 += (double)softplus_fast(z2[p]);
            }
        }
    }

    // per-atom epilogue (wave-local, double precision for h/pre path)
    double wf0, wf1, wf2;
    {
        epid[wave][lane] = us0;
        double acc = 0.0;
        for (int m = 0; m < 64; ++m) acc += epid[wave][m] * (double)W2a[m*64 + f];
        wf0 = 1.0 + acc + 127.0 * (double)b2a[f];

        epid[wave][lane] = us1;
        double acc1 = 0.0;
        for (int m = 0; m < 64; ++m) acc1 += epid[wave][m] * (double)W2b[m*64 + f];
        wf1 = 1.0 + acc1 + 127.0 * (double)b2b[f];

        epid[wave][lane] = us2;
        double acc2 = 0.0;
        for (int m = 0; m < 64; ++m) acc2 += epid[wave][m] * (double)W2c[m*64 + f];
        wf2 = 1.0 + acc2 + 127.0 * (double)b2c[f];
    }
    double h0 = (double)Wenc[f] + (double)benc[f];
    double h  = h0 * wf0 * wf1 * wf2;
    epid[wave][lane] = h;
    double pre = (double)bt1[lane];
    for (int m = 0; m < 64; ++m) pre += epid[wave][m] * (double)Wt1[m*64 + lane];
    double tv = tanh(pre);
    float gv = (float)((1.0 - tv * tv) * (double)Wt2[lane]);

    float p1 = (float)(h0 * wf1 * wf2);   // pairs with layer a
    float p2 = (float)(h0 * wf0 * wf2);   // layer b
    float p3 = (float)(h0 * wf0 * wf1);   // layer c

    // fused: dv = g @ Wt1^T
    epif[wave][lane] = gv;
    float dv = 0.f;
    for (int m = 0; m < 64; ++m) dv = fmaf(epif[wave][m], Wt1[lane*64 + m], dv);

    float* co = Cout + atom * 192;
    epif[wave][lane] = dv * p1;
    float c0 = 0.f;
    for (int m = 0; m < 64; ++m) c0 = fmaf(epif[wave][m], W2a[lane*64 + m], c0);
    co[lane] = c0;

    epif[wave][lane] = dv * p2;
    float c1 = 0.f;
    for (int m = 0; m < 64; ++m) c1 = fmaf(epif[wave][m], W2b[lane*64 + m], c1);
    co[64 + lane] = c1;

    epif[wave][lane] = dv * p3;
    float c2 = 0.f;
    for (int m = 0; m < 64; ++m) c2 = fmaf(epif[wave][m], W2c[lane*64 + m], c2);
    co[128 + lane] = c2;
}

// ------- backward v3: f-lane layout, unordered pairs, PT=8 pair register tile -------
// 1024-thread block = 16 atom-waves sharing one (w,u) LDS table.
// wave = atom i; t-tiles of 8 offsets; lane = feature f.
__global__ __launch_bounds__(1024, 4) void k_bwd(
    const float* __restrict__ dws,
    const float* __restrict__ mus, const float* __restrict__ gamma,
    const float2* __restrict__ wu,
    const float* __restrict__ b1a, const float* __restrict__ b1b, const float* __restrict__ b1c,
    const float* __restrict__ C, float* __restrict__ T)
{
    __shared__ float2 wus[3 * KK * FF];    // 76800 B  [l][k][f]
    __shared__ float  rbfs[16][KK][PT];    // 25600 B
    __shared__ float  dsh[16][PT];
    __shared__ float  mus_s[64];

    int tid = threadIdx.x;
    for (int idx = tid; idx < 3 * KK * FF; idx += 1024) wus[idx] = wu[idx];
    if (tid < KK) mus_s[tid] = mus[tid];
    __syncthreads();

    int wave = tid >> 6, lane = tid & 63;
    int atom = blockIdx.x * 16 + wave;
    int b = atom >> 7, i = atom & 127;
    float gam = gamma[0];
    float n2g = -2.f * gam;
    const float* drow = dws + (atom << 7);
    const float* ci = C + atom * 192;
    float ci0 = ci[lane], ci1 = ci[64 + lane], ci2 = ci[128 + lane];
    float bb0 = b1a[lane], bb1 = b1b[lane], bb2 = b1c[lane];
    float* Tb = T + ((size_t)b << 14);

    for (int t = 0; t < 8; ++t) {
        if (lane < PT) {
            int off = 1 + t * PT + lane;
            dsh[wave][lane] = drow[(i + off) & 127];
        }
        #pragma unroll
        for (int pass = 0; pass < 7; ++pass) {
            int idx = lane + (pass << 6);
            if (idx < KK * PT) {
                int k = idx >> 3, p = idx & 7;
                float dd = dsh[wave][p] - mus_s[k];
                rbfs[wave][k][p] = __expf(-gam * dd * dd);
            }
        }
        float z0[PT], z1[PT], z2[PT], v0[PT], v1[PT], v2[PT];
        #pragma unroll
        for (int p = 0; p < PT; ++p) {
            z0[p] = 0.f; z1[p] = 0.f; z2[p] = 0.f;
            v0[p] = 0.f; v1[p] = 0.f; v2[p] = 0.f;
        }
        #pragma unroll 2
        for (int k = 0; k < KK; ++k) {
            float2 w0 = wus[(k << 6) + lane];
            float2 w1 = wus[KK * FF + (k << 6) + lane];
            float2 w2 = wus[2 * KK * FF + (k << 6) + lane];
            float rr[PT];
            {
                const float4* rp4 = (const float4*)(&rbfs[wave][k][0]);
                float4 a0 = rp4[0], a1 = rp4[1];
                *(float4*)&rr[0] = a0; *(float4*)&rr[4] = a1;
            }
            #pragma unroll
            for (int p = 0; p < PT; ++p) {
                z0[p] = fmaf(rr[p], w0.x, z0[p]);
                v0[p] = fmaf(rr[p], w0.y, v0[p]);
                z1[p] = fmaf(rr[p], w1.x, z1[p]);
                v1[p] = fmaf(rr[p], w1.y, v1[p]);
                z2[p] = fmaf(rr[p], w2.x, z2[p]);
                v2[p] = fmaf(rr[p], w2.y, v2[p]);
            }
        }
        float vmine = 0.f;
        #pragma unroll
        for (int p = 0; p < PT; ++p) {
            float d = dsh[wave][p];
            float n2gd = n2g * d;
            float zb0 = z0[p] + bb0, zb1 = z1[p] + bb1, zb2 = z2[p] + bb2;
            float s0 = __builtin_amdgcn_rcpf(1.f + __expf(-zb0));
            float s1 = __builtin_amdgcn_rcpf(1.f + __expf(-zb1));
            float s2 = __builtin_amdgcn_rcpf(1.f + __expf(-zb2));
            float y0 = fmaf(n2gd, z0[p], v0[p]);
            float y1 = fmaf(n2gd, z1[p], v1[p]);
            float y2 = fmaf(n2gd, z2[p], v2[p]);
            float g0 = s0 * y0, g1 = s1 * y1, g2 = s2 * y2;
            int a = (i + 1 + t * PT + p) & 127;
            const float* ca = C + (((b << 7) + a) * 192);
            float red = fmaf(ci0, g0, fmaf(ci1, g1, ci2 * g2));
            red = fmaf(ca[lane], g0, red);
            red = fmaf(ca[64 + lane], g1, red);
            red = fmaf(ca[128 + lane], g2, red);
            #pragma unroll
            for (int o = 1; o < 64; o <<= 1) red += __shfl_xor(red, o);
            if (lane == p) vmine = red;
        }
        if (lane < PT) {
            int off = 1 + t * PT + lane;
            if (off < 64 || i < 64) {
                int a = (i + off) & 127;
                Tb[(i << 7) + a] = vmine;
                Tb[(a << 7) + i] = vmine;
            }
        }
    }
}

__global__ __launch_bounds__(256) void k_force(
    const float* __restrict__ xs, const float* __restrict__ dws,
    const float* __restrict__ T, float* __restrict__ Fr)
{
    int tid = threadIdx.x;
    int wave = tid >> 6, lane = tid & 63;
    int atom = blockIdx.x * 4 + wave;
    int i = atom & 127;
    int b = atom >> 7;
    const float* xb = xs + b * (NN * 3);
    float xi0 = xb[i*3], xi1 = xb[i*3+1], xi2 = xb[i*3+2];
    const float* drow = dws + (atom << 7);
    const float* trow = T + (atom << 7);
    float fx = 0.f, fy = 0.f, fz = 0.f;
    for (int it = lane; it < 127; it += 64) {
        int aa = (i + 1 + it) & 127;
        float coef = trow[aa] / drow[aa];
        fx += coef * (xi0 - xb[aa*3]);
        fy += coef * (xi1 - xb[aa*3+1]);
        fz += coef * (xi2 - xb[aa*3+2]);
    }
    #pragma unroll
    for (int off = 1; off < 64; off <<= 1) {
        fx += __shfl_xor(fx, off);
        fy += __shfl_xor(fy, off);
        fz += __shfl_xor(fz, off);
    }
    if (lane == 0) {
        Fr[atom*3]   = fx;
        Fr[atom*3+1] = fy;
        Fr[atom*3+2] = fz;
    }
}

__global__ __launch_bounds__(128) void k_out(const float* __restrict__ Fr, float* __restrict__ out)
{
    __shared__ float rs[3][128];
    int b = blockIdx.x, n = threadIdx.x;
    float g0 = Fr[(b*128+n)*3], g1 = Fr[(b*128+n)*3+1], g2 = Fr[(b*128+n)*3+2];
    rs[0][n] = g0; rs[1][n] = g1; rs[2][n] = g2;
    __syncthreads();
    for (int s = 64; s > 0; s >>= 1) {
        if (n < s) {
            rs[0][n] += rs[0][n+s];
            rs[1][n] += rs[1][n+s];
            rs[2][n] += rs[2][n+s];
        }
        __syncthreads();
    }
    float m0 = rs[0][0] * (1.f/128.f);
    float m1 = rs[1][0] * (1.f/128.f);
    float m2 = rs[2][0] * (1.f/128.f);
    out[b*384 + n*3 + 0] = m0 - g0;
    out[b*384 + n*3 + 1] = m1 - g1;
    out[b*384 + n*3 + 2] = m2 - g2;
}

extern "C" void kernel_launch(void* const* d_in, const int* in_sizes, int n_in,
                              void* d_out, int out_size, void* d_ws, size_t ws_size,
                              hipStream_t stream)
{
    const float* xs   = (const float*)d_in[1];
    const float* mus  = (const float*)d_in[2];
    const float* gam  = (const float*)d_in[3];
    const float* Wenc = (const float*)d_in[4];
    const float* benc = (const float*)d_in[5];
    const float* W1a  = (const float*)d_in[6];
    const float* b1a  = (const float*)d_in[7];
    const float* W2a  = (const float*)d_in[8];
    const float* b2a  = (const float*)d_in[9];
    const float* W1b  = (const float*)d_in[10];
    const float* b1b  = (const float*)d_in[11];
    const float* W2b  = (const float*)d_in[12];
    const float* b2b  = (const float*)d_in[13];
    const float* W1c  = (const float*)d_in[14];
    const float* b1c  = (const float*)d_in[15];
    const float* W2c  = (const float*)d_in[16];
    const float* b2c  = (const float*)d_in[17];
    const float* Wt1  = (const float*)d_in[18];
    const float* bt1  = (const float*)d_in[19];
    const float* Wt2  = (const float*)d_in[20];

    float* ws  = (float*)d_ws;
    float* dws = ws;
    float* T   = ws + 524288;
    float2* wu = (float2*)(ws + 1048576);
    float* C   = ws + 2097152;
    float* Fr  = ws + 2883584;
    float* out = (float*)d_out;

    k_dist <<<2048, 256, 0, stream>>>(xs, dws);
    k_prep <<<38, 256, 0, stream>>>(W1a, W1b, W1c, mus, gam, wu);
    k_fwd  <<<512, 512, 0, stream>>>(dws, mus, gam, W1a, W1b, W1c, b1a, b1b, b1c,
                                     W2a, W2b, W2c, b2a, b2b, b2c, Wenc, benc,
                                     Wt1, bt1, Wt2, C);
    k_bwd  <<<256, 1024, 0, stream>>>(dws, mus, gam, wu, b1a, b1b, b1c, C, T);
    k_force<<<1024, 256, 0, stream>>>(xs, dws, T, Fr);
    k_out  <<<32, 128, 0, stream>>>(Fr, out);
}

// Round 8
// 341.194 us; speedup vs baseline: 3.4757x; 1.0063x over previous
//
#include <hip/hip_runtime.h>
#include <math.h>

#define NN 128
#define FF 64
#define KK 50
#define PT 8
#define EPSV 1e-6f

// ws layout (floats):
// dws: [B*N*N]      off 0         (524288)
// T:   [B*N*N]      off 524288    (s_ia + s_ai, both orderings filled)
// wu:  [3*50*64*2]  off 1048576   (W1 and u=2*gamma*mu_k*W1, interleaved)
// C:   [B*N*3*64]   off 2097152
// Fr:  [B*N*3]      off 2883584

__device__ __forceinline__ float softplus_fast(float z) {
    float e = __expf(-fabsf(z));
    float l = __logf(1.f + e);
    return fmaxf(z, 0.f) + l;
}

__global__ __launch_bounds__(256) void k_dist(const float* __restrict__ xs, float* __restrict__ dws)
{
    int tid = blockIdx.x * 256 + threadIdx.x;
    int b = tid >> 14;
    int rem = tid & 16383;
    int i = rem >> 7, a = rem & 127;
    const float* xb = xs + b * (NN * 3);
    float dx = xb[i*3+0] - xb[a*3+0];
    float dy = xb[i*3+1] - xb[a*3+1];
    float dz = xb[i*3+2] - xb[a*3+2];
    dws[tid] = sqrtf(dx*dx + dy*dy + dz*dz + EPSV);
}

// build (w, u) pairs: u[l][k][f] = 2*gamma*mu_k * W1l[k][f]
__global__ __launch_bounds__(256) void k_prep(
    const float* __restrict__ W1a, const float* __restrict__ W1b, const float* __restrict__ W1c,
    const float* __restrict__ mus, const float* __restrict__ gamma,
    float2* __restrict__ wu)
{
    int idx = blockIdx.x * 256 + threadIdx.x;   // 3*50*64 = 9600
    if (idx < 3 * KK * FF) {
        int l = idx / (KK * FF), r = idx - l * (KK * FF);
        int k = r >> 6;
        const float* W = (l == 0) ? W1a : (l == 1) ? W1b : W1c;
        float w = W[r];
        wu[idx] = make_float2(w, 2.f * gamma[0] * mus[k] * w);
    }
}

// ------- forward (+ fused per-atom backward weights): 8 waves/block -------
__global__ __launch_bounds__(512, 2) void k_fwd(
    const float* __restrict__ dws,
    const float* __restrict__ mus, const float* __restrict__ gamma,
    const float* __restrict__ W1a, const float* __restrict__ W1b, const float* __restrict__ W1c,
    const float* __restrict__ b1a, const float* __restrict__ b1b, const float* __restrict__ b1c,
    const float* __restrict__ W2a, const float* __restrict__ W2b, const float* __restrict__ W2c,
    const float* __restrict__ b2a, const float* __restrict__ b2b, const float* __restrict__ b2c,
    const float* __restrict__ Wenc, const float* __restrict__ benc,
    const float* __restrict__ Wt1, const float* __restrict__ bt1, const float* __restrict__ Wt2,
    float* __restrict__ Cout)
{
    __shared__ float2 wab[KK * FF];       // (wa,wb)  25600 B
    __shared__ float  wcs[KK * FF];       // wc       12800 B
    __shared__ float  rbfs[8][KK][16];    // 25600 B
    __shared__ float  dsh[8][16];
    __shared__ float  mus_s[64];
    __shared__ double epid[8][FF];
    __shared__ float  epif[8][FF];

    int tid = threadIdx.x;
    for (int idx = tid; idx < KK * FF; idx += 512) {
        wab[idx] = make_float2(W1a[idx], W1b[idx]);
        wcs[idx] = W1c[idx];
    }
    if (tid < KK) mus_s[tid] = mus[tid];
    __syncthreads();

    int wave = tid >> 6, lane = tid & 63, f = lane;
    int atom = blockIdx.x * 8 + wave;
    int i = atom & 127;
    float gam = gamma[0];
    float bb0 = b1a[f], bb1 = b1b[f], bb2 = b1c[f];
    double us0 = 0.0, us1 = 0.0, us2 = 0.0;
    const float* drow = dws + (atom << 7);

    for (int t = 0; t < 8; ++t) {
        if (lane < 16) {
            int aa = (i + 1 + 16 * t + lane) & 127;
            dsh[wave][lane] = drow[aa];
        }
        #pragma unroll
        for (int pass = 0; pass < 13; ++pass) {
            int idx = lane + (pass << 6);
            int k = idx >> 4, p = idx & 15;
            if (k < KK) {
                float dd = dsh[wave][p] - mus_s[k];
                rbfs[wave][k][p] = __expf(-gam * dd * dd);
            }
        }
        float z0[16], z1[16], z2[16];
        #pragma unroll
        for (int p = 0; p < 16; ++p) { z0[p] = bb0; z1[p] = bb1; z2[p] = bb2; }
        #pragma unroll 2
        for (int k = 0; k < KK; ++k) {
            float2 wv = wab[(k << 6) + f];
            float  wc = wcs[(k << 6) + f];
            float rr[16];
            {
                const float4* rp4 = (const float4*)(&rbfs[wave][k][0]);
                float4 a0 = rp4[0], a1 = rp4[1], a2 = rp4[2], a3 = rp4[3];
                *(float4*)&rr[0]  = a0; *(float4*)&rr[4]  = a1;
                *(float4*)&rr[8]  = a2; *(float4*)&rr[12] = a3;
            }
            #pragma unroll
            for (int p = 0; p < 16; ++p) {
                z0[p] = fmaf(rr[p], wv.x, z0[p]);
                z1[p] = fmaf(rr[p], wv.y, z1[p]);
                z2[p] = fmaf(rr[p], wc,   z2[p]);
            }
        }
        int base = 16 * t;
        #pragma unroll
        for (int p = 0; p < 16; ++p) {
            if (base + p < 127) {
                us0 += (double)softplus_fast(z0[p]);
                us1 += (double)softplus_fast(z1[p]);
                us2 += (double)softplus_fast(z2[p]);
            }
        }
    }

    // per-atom epilogue (wave-local, double precision for h/pre path)
    double wf0, wf1, wf2;
    {
        epid[wave][lane] = us0;
        double acc = 0.0;
        for (int m = 0; m < 64; ++m) acc += epid[wave][m] * (double)W2a[m*64 + f];
        wf0 = 1.0 + acc + 127.0 * (double)b2a[f];

        epid[wave][lane] = us1;
        double acc1 = 0.0;
        for (int m = 0; m < 64; ++m) acc1 += epid[wave][m] * (double)W2b[m*64 + f];
        wf1 = 1.0 + acc1 + 127.0 * (double)b2b[f];

        epid[wave][lane] = us2;
        double acc2 = 0.0;
        for (int m = 0; m < 64; ++m) acc2 += epid[wave][m] * (double)W2c[m*64 + f];
        wf2 = 1.0 + acc2 + 127.0 * (double)b2c[f];
    }
    double h0 = (double)Wenc[f] + (double)benc[f];
    double h  = h0 * wf0 * wf1 * wf2;
    epid[wave][lane] = h;
    double pre = (double)bt1[lane];
    for (int m = 0; m < 64; ++m) pre += epid[wave][m] * (double)Wt1[m*64 + lane];
    double tv = tanh(pre);
    float gv = (float)((1.0 - tv * tv) * (double)Wt2[lane]);

    float p1 = (float)(h0 * wf1 * wf2);   // pairs with layer a
    float p2 = (float)(h0 * wf0 * wf2);   // layer b
    float p3 = (float)(h0 * wf0 * wf1);   // layer c

    // fused: dv = g @ Wt1^T
    epif[wave][lane] = gv;
    float dv = 0.f;
    for (int m = 0; m < 64; ++m) dv = fmaf(epif[wave][m], Wt1[lane*64 + m], dv);

    float* co = Cout + atom * 192;
    epif[wave][lane] = dv * p1;
    float c0 = 0.f;
    for (int m = 0; m < 64; ++m) c0 = fmaf(epif[wave][m], W2a[lane*64 + m], c0);
    co[lane] = c0;

    epif[wave][lane] = dv * p2;
    float c1 = 0.f;
    for (int m = 0; m < 64; ++m) c1 = fmaf(epif[wave][m], W2b[lane*64 + m], c1);
    co[64 + lane] = c1;

    epif[wave][lane] = dv * p3;
    float c2 = 0.f;
    for (int m = 0; m < 64; ++m) c2 = fmaf(epif[wave][m], W2c[lane*64 + m], c2);
    co[128 + lane] = c2;
}

// ------- backward: f-lane layout, unordered pairs, PT=8 pair register tile -------
__global__ __launch_bounds__(1024, 4) void k_bwd(
    const float* __restrict__ dws,
    const float* __restrict__ mus, const float* __restrict__ gamma,
    const float2* __restrict__ wu,
    const float* __restrict__ b1a, const float* __restrict__ b1b, const float* __restrict__ b1c,
    const float* __restrict__ C, float* __restrict__ T)
{
    __shared__ float2 wus[3 * KK * FF];    // 76800 B  [l][k][f]
    __shared__ float  rbfs[16][KK][PT];    // 25600 B
    __shared__ float  dsh[16][PT];
    __shared__ float  mus_s[64];

    int tid = threadIdx.x;
    for (int idx = tid; idx < 3 * KK * FF; idx += 1024) wus[idx] = wu[idx];
    if (tid < KK) mus_s[tid] = mus[tid];
    __syncthreads();

    int wave = tid >> 6, lane = tid & 63;
    int atom = blockIdx.x * 16 + wave;
    int b = atom >> 7, i = atom & 127;
    float gam = gamma[0];
    float n2g = -2.f * gam;
    const float* drow = dws + (atom << 7);
    const float* ci = C + atom * 192;
    float ci0 = ci[lane], ci1 = ci[64 + lane], ci2 = ci[128 + lane];
    float bb0 = b1a[lane], bb1 = b1b[lane], bb2 = b1c[lane];
    float* Tb = T + ((size_t)b << 14);

    for (int t = 0; t < 8; ++t) {
        if (lane < PT) {
            int off = 1 + t * PT + lane;
            dsh[wave][lane] = drow[(i + off) & 127];
        }
        #pragma unroll
        for (int pass = 0; pass < 7; ++pass) {
            int idx = lane + (pass << 6);
            if (idx < KK * PT) {
                int k = idx >> 3, p = idx & 7;
                float dd = dsh[wave][p] - mus_s[k];
                rbfs[wave][k][p] = __expf(-gam * dd * dd);
            }
        }
        float z0[PT], z1[PT], z2[PT], v0[PT], v1[PT], v2[PT];
        #pragma unroll
        for (int p = 0; p < PT; ++p) {
            z0[p] = 0.f; z1[p] = 0.f; z2[p] = 0.f;
            v0[p] = 0.f; v1[p] = 0.f; v2[p] = 0.f;
        }
        #pragma unroll 2
        for (int k = 0; k < KK; ++k) {
            float2 w0 = wus[(k << 6) + lane];
            float2 w1 = wus[KK * FF + (k << 6) + lane];
            float2 w2 = wus[2 * KK * FF + (k << 6) + lane];
            float rr[PT];
            {
                const float4* rp4 = (const float4*)(&rbfs[wave][k][0]);
                float4 a0 = rp4[0], a1 = rp4[1];
                *(float4*)&rr[0] = a0; *(float4*)&rr[4] = a1;
            }
            #pragma unroll
            for (int p = 0; p < PT; ++p) {
                z0[p] = fmaf(rr[p], w0.x, z0[p]);
                v0[p] = fmaf(rr[p], w0.y, v0[p]);
                z1[p] = fmaf(rr[p], w1.x, z1[p]);
                v1[p] = fmaf(rr[p], w1.y, v1[p]);
                z2[p] = fmaf(rr[p], w2.x, z2[p]);
                v2[p] = fmaf(rr[p], w2.y, v2[p]);
            }
        }
        float vmine = 0.f;
        #pragma unroll
        for (int p = 0; p < PT; ++p) {
            float d = dsh[wave][p];
            float n2gd = n2g * d;
            float zb0 = z0[p] + bb0, zb1 = z1[p] + bb1, zb2 = z2[p] + bb2;
            float s0 = __builtin_amdgcn_rcpf(1.f + __expf(-zb0));
            float s1 = __builtin_amdgcn_rcpf(1.f + __expf(-zb1));
            float s2 = __builtin_amdgcn_rcpf(1.f + __expf(-zb2));
            float y0 = fmaf(n2gd, z0[p], v0[p]);
            float y1 = fmaf(n2gd, z1[p], v1[p]);
            float y2 = fmaf(n2gd, z2[p], v2[p]);
            float g0 = s0 * y0, g1 = s1 * y1, g2 = s2 * y2;
            int a = (i + 1 + t * PT + p) & 127;
            const float* ca = C + (((b << 7) + a) * 192);
            float red = fmaf(ci0, g0, fmaf(ci1, g1, ci2 * g2));
            red = fmaf(ca[lane], g0, red);
            red = fmaf(ca[64 + lane], g1, red);
            red = fmaf(ca[128 + lane], g2, red);
            #pragma unroll
            for (int o = 1; o < 64; o <<= 1) red += __shfl_xor(red, o);
            if (lane == p) vmine = red;
        }
        if (lane < PT) {
            int off = 1 + t * PT + lane;
            if (off < 64 || i < 64) {
                int a = (i + off) & 127;
                Tb[(i << 7) + a] = vmine;
                Tb[(a << 7) + i] = vmine;
            }
        }
    }
}

__global__ __launch_bounds__(256) void k_force(
    const float* __restrict__ xs, const float* __restrict__ dws,
    const float* __restrict__ T, float* __restrict__ Fr)
{
    int tid = threadIdx.x;
    int wave = tid >> 6, lane = tid & 63;
    int atom = blockIdx.x * 4 + wave;
    int i = atom & 127;
    int b = atom >> 7;
    const float* xb = xs + b * (NN * 3);
    float xi0 = xb[i*3], xi1 = xb[i*3+1], xi2 = xb[i*3+2];
    const float* drow = dws + (atom << 7);
    const float* trow = T + (atom << 7);
    float fx = 0.f, fy = 0.f, fz = 0.f;
    for (int it = lane; it < 127; it += 64) {
        int aa = (i + 1 + it) & 127;
        float coef = trow[aa] / drow[aa];
        fx += coef * (xi0 - xb[aa*3]);
        fy += coef * (xi1 - xb[aa*3+1]);
        fz += coef * (xi2 - xb[aa*3+2]);
    }
    #pragma unroll
    for (int off = 1; off < 64; off <<= 1) {
        fx += __shfl_xor(fx, off);
        fy += __shfl_xor(fy, off);
        fz += __shfl_xor(fz, off);
    }
    if (lane == 0) {
        Fr[atom*3]   = fx;
        Fr[atom*3+1] = fy;
        Fr[atom*3+2] = fz;
    }
}

__global__ __launch_bounds__(128) void k_out(const float* __restrict__ Fr, float* __restrict__ out)
{
    __shared__ float rs[3][128];
    int b = blockIdx.x, n = threadIdx.x;
    float g0 = Fr[(b*128+n)*3], g1 = Fr[(b*128+n)*3+1], g2 = Fr[(b*128+n)*3+2];
    rs[0][n] = g0; rs[1][n] = g1; rs[2][n] = g2;
    __syncthreads();
    for (int s = 64; s > 0; s >>= 1) {
        if (n < s) {
            rs[0][n] += rs[0][n+s];
            rs[1][n] += rs[1][n+s];
            rs[2][n] += rs[2][n+s];
        }
        __syncthreads();
    }
    float m0 = rs[0][0] * (1.f/128.f);
    float m1 = rs[1][0] * (1.f/128.f);
    float m2 = rs[2][0] * (1.f/128.f);
    out[b*384 + n*3 + 0] = m0 - g0;
    out[b*384 + n*3 + 1] = m1 - g1;
    out[b*384 + n*3 + 2] = m2 - g2;
}

extern "C" void kernel_launch(void* const* d_in, const int* in_sizes, int n_in,
                              void* d_out, int out_size, void* d_ws, size_t ws_size,
                              hipStream_t stream)
{
    const float* xs   = (const float*)d_in[1];
    const float* mus  = (const float*)d_in[2];
    const float* gam  = (const float*)d_in[3];
    const float* Wenc = (const float*)d_in[4];
    const float* benc = (const float*)d_in[5];
    const float* W1a  = (const float*)d_in[6];
    const float* b1a  = (const float*)d_in[7];
    const float* W2a  = (const float*)d_in[8];
    const float* b2a  = (const float*)d_in[9];
    const float* W1b  = (const float*)d_in[10];
    const float* b1b  = (const float*)d_in[11];
    const float* W2b  = (const float*)d_in[12];
    const float* b2b  = (const float*)d_in[13];
    const float* W1c  = (const float*)d_in[14];
    const float* b1c  = (const float*)d_in[15];
    const float* W2c  = (const float*)d_in[16];
    const float* b2c  = (const float*)d_in[17];
    const float* Wt1  = (const float*)d_in[18];
    const float* bt1  = (const float*)d_in[19];
    const float* Wt2  = (const float*)d_in[20];

    float* ws  = (float*)d_ws;
    float* dws = ws;
    float* T   = ws + 524288;
    float2* wu = (float2*)(ws + 1048576);
    float* C   = ws + 2097152;
    float* Fr  = ws + 2883584;
    float* out = (float*)d_out;

    k_dist <<<2048, 256, 0, stream>>>(xs, dws);
    k_prep <<<38, 256, 0, stream>>>(W1a, W1b, W1c, mus, gam, wu);
    k_fwd  <<<512, 512, 0, stream>>>(dws, mus, gam, W1a, W1b, W1c, b1a, b1b, b1c,
                                     W2a, W2b, W2c, b2a, b2b, b2c, Wenc, benc,
                                     Wt1, bt1, Wt2, C);
    k_bwd  <<<256, 1024, 0, stream>>>(dws, mus, gam, wu, b1a, b1b, b1c, C, T);
    k_force<<<1024, 256, 0, stream>>>(xs, dws, T, Fr);
    k_out  <<<32, 128, 0, stream>>>(Fr, out);
}